// Round 7
// baseline (148.054 us; speedup 1.0000x reference)
//
#include <hip/hip_runtime.h>

#define NN      4096   // total nodes
#define BG      64     // graphs
#define NPG_    64     // nodes per graph
#define LT_     128
#define LL_     32
#define D_      256
#define OUT_    1024
#define NPB8    8      // nodes per block (fused kernel)
#define BLK     512    // threads per block (8 waves)

// ---------------- Fused gather + projection ----------------
// 512 blocks x 512 thr (8 waves), 8 nodes/block -> 2 blocks/CU, 16 waves/CU.
// W (Wg_text+Wg_label, 512 KB) is read once per block -> 256 MB total L2-path.
// Phases: ids->LDS; 8-way wave-split ragged gathers -> 2-round LDS reduce -> xT/xL;
// k-split proj (wave w owns k in [32w,32w+32)), lane owns 4 cols x 8 nodes;
// 2-round LDS k-reduce, relu, w_adap combine, coalesced write. Fixed-order -> deterministic.
__global__ __launch_bounds__(BLK, 4) void fused_kernel(
    const int*   __restrict__ text_ids,
    const int*   __restrict__ label_ids,
    const int*   __restrict__ text_len,
    const int*   __restrict__ label_len,
    const float* __restrict__ word_emb,
    const float* __restrict__ label_emb,
    const float* __restrict__ Wg_text,
    const float* __restrict__ Wg_label,
    const float* __restrict__ w_adap,
    float*       __restrict__ h_comb)     // [NN, D]
{
    __shared__ int   sIds[NPB8][LT_ + LL_];   // 5 KB
    __shared__ float red4[4][NPB8 * D_];      // 32 KB, time-multiplexed
    __shared__ float xT[NPB8][D_ + 8];        // 8.25 KB
    __shared__ float xL[NPB8][D_ + 8];        // 8.25 KB
    __shared__ int   sLT[NPB8], sLL[NPB8];
    __shared__ float sInvT[NPB8];

    const int tid  = threadIdx.x;
    const int wave = tid >> 6;
    const int lane = tid & 63;
    const int base = blockIdx.x * NPB8;

    // ---- Phase 1: stage ids + lens (coalesced) ----
    #pragma unroll
    for (int r = 0; r < 2; ++r) {             // NPB8*LT_ = 1024 = 2*BLK
        const int idx = tid + BLK * r;
        const int nd = idx >> 7, t = idx & (LT_ - 1);
        sIds[nd][t] = text_ids[(size_t)(base + nd) * LT_ + t];
    }
    if (tid < NPB8 * LL_) {
        const int nd = tid >> 5, t = tid & (LL_ - 1);
        sIds[nd][LT_ + t] = label_ids[(size_t)(base + nd) * LL_ + t];
    }
    if (tid < NPB8) {
        const int l = text_len[base + tid];
        sLT[tid] = l;
        sInvT[tid] = 1.0f / (float)l;
        sLL[tid] = label_len[base + tid];
    }
    __syncthreads();

    // ---- Phase 2: ragged gathers (wave w takes rows l = w, w+8, ...) ----
    float4 aT[NPB8], aL[NPB8];
    {
        const float* __restrict__ bp = word_emb + (size_t)lane * 4;
        #pragma unroll
        for (int nd = 0; nd < NPB8; ++nd) {
            const int L = sLT[nd];
            float4 a = make_float4(0.f, 0.f, 0.f, 0.f);
            #pragma unroll 4
            for (int l = wave; l < L; l += 8) {
                const float4 v = *reinterpret_cast<const float4*>(
                    bp + (size_t)sIds[nd][l] * D_);
                a.x += v.x; a.y += v.y; a.z += v.z; a.w += v.w;
            }
            aT[nd] = a;
        }
    }
    {
        const float* __restrict__ bp = label_emb + (size_t)lane * 4;
        #pragma unroll
        for (int nd = 0; nd < NPB8; ++nd) {
            const int L = sLL[nd];
            float4 a = make_float4(0.f, 0.f, 0.f, 0.f);
            #pragma unroll 2
            for (int l = wave; l < L; l += 8) {
                const float4 v = *reinterpret_cast<const float4*>(
                    bp + (size_t)sIds[nd][LT_ + l] * D_);
                a.x += v.x; a.y += v.y; a.z += v.z; a.w += v.w;
            }
            aL[nd] = a;
        }
    }

    // ---- text reduce: 2 rounds into red4, then spread ----
    if (wave < 4) {
        #pragma unroll
        for (int nd = 0; nd < NPB8; ++nd)
            *reinterpret_cast<float4*>(&red4[wave][nd * D_ + lane * 4]) = aT[nd];
    }
    __syncthreads();
    if (wave >= 4) {
        #pragma unroll
        for (int nd = 0; nd < NPB8; ++nd) {
            float4* p = reinterpret_cast<float4*>(&red4[wave - 4][nd * D_ + lane * 4]);
            float4 v = *p;
            v.x += aT[nd].x; v.y += aT[nd].y; v.z += aT[nd].z; v.w += aT[nd].w;
            *p = v;
        }
    }
    __syncthreads();
    #pragma unroll
    for (int i = 0; i < 4; ++i) {
        const int idx = tid + BLK * i;
        const int nd = idx >> 8, col = idx & 255;
        const float v = (red4[0][idx] + red4[1][idx]) + (red4[2][idx] + red4[3][idx]);
        xT[nd][col] = v * sInvT[nd];
    }
    __syncthreads();
    // ---- label reduce (reuse red4) ----
    if (wave < 4) {
        #pragma unroll
        for (int nd = 0; nd < NPB8; ++nd)
            *reinterpret_cast<float4*>(&red4[wave][nd * D_ + lane * 4]) = aL[nd];
    }
    __syncthreads();
    if (wave >= 4) {
        #pragma unroll
        for (int nd = 0; nd < NPB8; ++nd) {
            float4* p = reinterpret_cast<float4*>(&red4[wave - 4][nd * D_ + lane * 4]);
            float4 v = *p;
            v.x += aL[nd].x; v.y += aL[nd].y; v.z += aL[nd].z; v.w += aL[nd].w;
            *p = v;
        }
    }
    __syncthreads();
    #pragma unroll
    for (int i = 0; i < 4; ++i) {
        const int idx = tid + BLK * i;
        const int nd = idx >> 8, col = idx & 255;
        xL[nd][col] = (red4[0][idx] + red4[1][idx]) + (red4[2][idx] + red4[3][idx]);
    }
    __syncthreads();

    // ---- Phase 3: k-split projection (wave owns k in [32w, 32w+32)) ----
    float pT[NPB8][4], pL[NPB8][4];
    #pragma unroll
    for (int nd = 0; nd < NPB8; ++nd) {
        #pragma unroll
        for (int j = 0; j < 4; ++j) { pT[nd][j] = 0.f; pL[nd][j] = 0.f; }
    }
    const int c0 = lane * 4;
    const int k0 = wave * 32;

    for (int kk = 0; kk < 32; kk += 4) {
        const int k = k0 + kk;
        float xt[NPB8][4], xl[NPB8][4];
        #pragma unroll
        for (int nd = 0; nd < NPB8; ++nd) {
            const float4 a = *reinterpret_cast<const float4*>(&xT[nd][k]);
            const float4 b = *reinterpret_cast<const float4*>(&xL[nd][k]);
            xt[nd][0] = a.x; xt[nd][1] = a.y; xt[nd][2] = a.z; xt[nd][3] = a.w;
            xl[nd][0] = b.x; xl[nd][1] = b.y; xl[nd][2] = b.z; xl[nd][3] = b.w;
        }
        #pragma unroll
        for (int dk = 0; dk < 4; ++dk) {
            const size_t ro = (size_t)(k + dk) * D_ + c0;
            const float4 wt = *reinterpret_cast<const float4*>(Wg_text  + ro);
            const float4 wl = *reinterpret_cast<const float4*>(Wg_label + ro);
            #pragma unroll
            for (int nd = 0; nd < NPB8; ++nd) {
                const float xv = xt[nd][dk];
                pT[nd][0] = fmaf(xv, wt.x, pT[nd][0]);
                pT[nd][1] = fmaf(xv, wt.y, pT[nd][1]);
                pT[nd][2] = fmaf(xv, wt.z, pT[nd][2]);
                pT[nd][3] = fmaf(xv, wt.w, pT[nd][3]);
                const float yv = xl[nd][dk];
                pL[nd][0] = fmaf(yv, wl.x, pL[nd][0]);
                pL[nd][1] = fmaf(yv, wl.y, pL[nd][1]);
                pL[nd][2] = fmaf(yv, wl.z, pL[nd][2]);
                pL[nd][3] = fmaf(yv, wl.w, pL[nd][3]);
            }
        }
    }

    // ---- Phase 4: k-reduction (2 rounds) + combine ----
    // text partials
    if (wave < 4) {
        #pragma unroll
        for (int nd = 0; nd < NPB8; ++nd)
            *reinterpret_cast<float4*>(&red4[wave][nd * D_ + c0]) =
                make_float4(pT[nd][0], pT[nd][1], pT[nd][2], pT[nd][3]);
    }
    __syncthreads();
    if (wave >= 4) {
        #pragma unroll
        for (int nd = 0; nd < NPB8; ++nd) {
            float4* p = reinterpret_cast<float4*>(&red4[wave - 4][nd * D_ + c0]);
            float4 v = *p;
            v.x += pT[nd][0]; v.y += pT[nd][1]; v.z += pT[nd][2]; v.w += pT[nd][3];
            *p = v;
        }
    }
    __syncthreads();
    float rT[4];
    #pragma unroll
    for (int i = 0; i < 4; ++i) {
        const int idx = tid + BLK * i;
        rT[i] = (red4[0][idx] + red4[1][idx]) + (red4[2][idx] + red4[3][idx]);
    }
    __syncthreads();
    // label partials
    if (wave < 4) {
        #pragma unroll
        for (int nd = 0; nd < NPB8; ++nd)
            *reinterpret_cast<float4*>(&red4[wave][nd * D_ + c0]) =
                make_float4(pL[nd][0], pL[nd][1], pL[nd][2], pL[nd][3]);
    }
    __syncthreads();
    if (wave >= 4) {
        #pragma unroll
        for (int nd = 0; nd < NPB8; ++nd) {
            float4* p = reinterpret_cast<float4*>(&red4[wave - 4][nd * D_ + c0]);
            float4 v = *p;
            v.x += pL[nd][0]; v.y += pL[nd][1]; v.z += pL[nd][2]; v.w += pL[nd][3];
            *p = v;
        }
    }
    __syncthreads();

    const float w0 = w_adap[0] * (1.0f / (float)NPG_);
    const float w1 = w_adap[1] * (1.0f / (float)NPG_);
    #pragma unroll
    for (int i = 0; i < 4; ++i) {
        const int idx = tid + BLK * i;
        const int nd = idx >> 8, col = idx & 255;
        const float rL = (red4[0][idx] + red4[1][idx]) + (red4[2][idx] + red4[3][idx]);
        const float ht = rT[i] > 0.f ? rT[i] : 0.f;
        const float hl = rL    > 0.f ? rL    : 0.f;
        h_comb[(size_t)(base + nd) * D_ + col] = w0 * ht + w1 * hl;
    }
}

// ---------------- Kernel C: per-graph readout + MLP, 4 blocks per graph split Wout ----------------
__global__ __launch_bounds__(256) void graph_kernel(
    const float* __restrict__ h_comb,   // [NN, D]
    const float* __restrict__ W1,       // [D, D]
    const float* __restrict__ b1,       // [D]
    const float* __restrict__ Wout,     // [D, OUT]
    const float* __restrict__ bout,     // [OUT]
    float*       __restrict__ out)      // [BG, OUT]
{
    __shared__ float fused[D_];
    __shared__ float hrow[D_];

    const int bx   = blockIdx.x;
    const int b    = bx >> 2;
    const int part = bx & 3;
    const int tid  = threadIdx.x;

    float acc = 0.f;
    const float* __restrict__ basep = h_comb + (size_t)b * NPG_ * D_ + tid;
    #pragma unroll 8
    for (int n = 0; n < NPG_; ++n) acc += basep[(size_t)n * D_];
    fused[tid] = acc;
    __syncthreads();

    float a1 = b1[tid];
    for (int d = 0; d < D_; ++d)
        a1 = fmaf(fused[d], W1[(size_t)d * D_ + tid], a1);
    hrow[tid] = a1 > 0.f ? a1 : 0.f;
    __syncthreads();

    const int j = part * 256 + tid;
    float o = bout[j];
    for (int d = 0; d < D_; ++d)
        o = fmaf(hrow[d], Wout[(size_t)d * OUT_ + j], o);
    out[(size_t)b * OUT_ + j] = o;
}

extern "C" void kernel_launch(void* const* d_in, const int* in_sizes, int n_in,
                              void* d_out, int out_size, void* d_ws, size_t ws_size,
                              hipStream_t stream) {
    const int*   text_ids  = (const int*)  d_in[0];
    const int*   label_ids = (const int*)  d_in[1];
    const int*   text_len  = (const int*)  d_in[2];
    const int*   label_len = (const int*)  d_in[3];
    const float* word_emb  = (const float*)d_in[4];
    const float* label_emb = (const float*)d_in[5];
    const float* Wg_text   = (const float*)d_in[6];
    const float* Wg_label  = (const float*)d_in[7];
    const float* w_adap    = (const float*)d_in[8];
    const float* W1        = (const float*)d_in[9];
    const float* b1        = (const float*)d_in[10];
    const float* Wout      = (const float*)d_in[11];
    const float* bout      = (const float*)d_in[12];

    float* h_comb = (float*)d_ws;      // 4 MiB scratch
    float* out    = (float*)d_out;

    fused_kernel<<<NN / NPB8, BLK, 0, stream>>>(
        text_ids, label_ids, text_len, label_len,
        word_emb, label_emb, Wg_text, Wg_label, w_adap, h_comb);

    graph_kernel<<<BG * 4, 256, 0, stream>>>(
        h_comb, W1, b1, Wout, bout, out);
}

// Round 8
// 113.977 us; speedup vs baseline: 1.2990x; 1.2990x over previous
//
#include <hip/hip_runtime.h>

#define NN      4096   // total nodes
#define BG      64     // graphs
#define NPG_    64     // nodes per graph
#define LT_     128
#define LL_     32
#define D_      256
#define OUT_    1024
#define PNPB    16     // nodes per block (proj kernel)

// ---------------- Kernel A: ragged gathers, 1 node/block, ids staged in LDS ----------------
// (identical to the proven R4 version: 59 us @ 2.9 TB/s)
__global__ __launch_bounds__(256) void gather_kernel(
    const int*   __restrict__ text_ids,
    const int*   __restrict__ label_ids,
    const int*   __restrict__ text_len,
    const int*   __restrict__ label_len,
    const float* __restrict__ word_emb,
    const float* __restrict__ label_emb,
    float*       __restrict__ text_out,   // [NN, D]
    float*       __restrict__ label_out)  // [NN, D]
{
    __shared__ int   sIds[LT_ + LL_];
    __shared__ float redT[4][D_];
    __shared__ float redL[4][D_];

    const int n    = blockIdx.x;
    const int tid  = threadIdx.x;
    const int wave = tid >> 6;
    const int lane = tid & 63;

    if (tid < LT_)               sIds[tid] = text_ids [(size_t)n * LT_ + tid];
    else if (tid < LT_ + LL_)    sIds[tid] = label_ids[(size_t)n * LL_ + (tid - LT_)];
    const int lt = text_len[n];
    const int ll = label_len[n];
    __syncthreads();

    float4 aT = make_float4(0.f, 0.f, 0.f, 0.f);
    float4 aL = make_float4(0.f, 0.f, 0.f, 0.f);

    {   // text partial sum: wave w takes l = w, w+4, ...
        const float* __restrict__ bp = word_emb + (size_t)lane * 4;
        #pragma unroll 8
        for (int l = wave; l < lt; l += 4) {
            const float4 v = *reinterpret_cast<const float4*>(bp + (size_t)sIds[l] * D_);
            aT.x += v.x; aT.y += v.y; aT.z += v.z; aT.w += v.w;
        }
    }
    {   // label partial sum
        const float* __restrict__ bp = label_emb + (size_t)lane * 4;
        #pragma unroll 8
        for (int l = wave; l < ll; l += 4) {
            const float4 v = *reinterpret_cast<const float4*>(bp + (size_t)sIds[LT_ + l] * D_);
            aL.x += v.x; aL.y += v.y; aL.z += v.z; aL.w += v.w;
        }
    }

    *reinterpret_cast<float4*>(&redT[wave][lane * 4]) = aT;
    *reinterpret_cast<float4*>(&redL[wave][lane * 4]) = aL;
    __syncthreads();

    const float t  = (redT[0][tid] + redT[1][tid]) + (redT[2][tid] + redT[3][tid]);
    const float lv = (redL[0][tid] + redL[1][tid]) + (redL[2][tid] + redL[3][tid]);
    text_out [(size_t)n * D_ + tid] = t / (float)lt;
    label_out[(size_t)n * D_ + tid] = lv;
}

// ---------------- Kernel B: broadcast projection ----------------
// 256 blocks x 512 thr, 16 nodes/block. Waves 0-3: text matrix, wave w owns cols
// [w*64, w*64+64), lane owns 1 col. Waves 4-7: label matrix likewise.
// x via LDS float4 broadcast (conflict-free); W via coalesced dword loads, each
// value reused across 16 nodes in registers. Label waves deposit w1*relu into
// LDS; text waves combine and store. Fixed-order FMA chains -> deterministic.
__global__ __launch_bounds__(512, 2) void proj_kernel(
    const float* __restrict__ text_out,   // [NN, D]
    const float* __restrict__ label_out,  // [NN, D]
    const float* __restrict__ Wg_text,
    const float* __restrict__ Wg_label,
    const float* __restrict__ w_adap,
    float*       __restrict__ h_comb)     // [NN, D] (may alias text_out; rows disjoint/block)
{
    __shared__ float xT[PNPB][D_ + 4];    // 16.6 KB
    __shared__ float xL[PNPB][D_ + 4];    // 16.6 KB
    __shared__ float hl[PNPB][D_];        // 16 KB: label waves' w1*relu results

    const int tid  = threadIdx.x;
    const int wave = tid >> 6;
    const int lane = tid & 63;
    const int base = blockIdx.x * PNPB;
    const bool isText = (wave < 4);
    const int jc = (isText ? wave : wave - 4) * 64 + lane;   // owned column

    // ---- stage x (coalesced float4, 2 rounds) ----
    #pragma unroll
    for (int r = 0; r < 2; ++r) {
        const int idx = tid + 512 * r;          // 0 .. 1023
        const int nd = idx >> 6;
        const int q4 = (idx & 63) * 4;
        *reinterpret_cast<float4*>(&xT[nd][q4]) =
            *reinterpret_cast<const float4*>(text_out  + (size_t)(base + nd) * D_ + q4);
        *reinterpret_cast<float4*>(&xL[nd][q4]) =
            *reinterpret_cast<const float4*>(label_out + (size_t)(base + nd) * D_ + q4);
    }
    __syncthreads();

    const float* __restrict__ W = isText ? Wg_text : Wg_label;
    const float (* __restrict__ X)[D_ + 4] = isText ? xT : xL;

    float acc[PNPB];
    #pragma unroll
    for (int nd = 0; nd < PNPB; ++nd) acc[nd] = 0.f;

    #pragma unroll 2
    for (int k4 = 0; k4 < D_; k4 += 4) {
        // 4 coalesced W dwords (reused across all 16 nodes)
        const float wk0 = W[(size_t)(k4 + 0) * D_ + jc];
        const float wk1 = W[(size_t)(k4 + 1) * D_ + jc];
        const float wk2 = W[(size_t)(k4 + 2) * D_ + jc];
        const float wk3 = W[(size_t)(k4 + 3) * D_ + jc];
        #pragma unroll
        for (int nd = 0; nd < PNPB; ++nd) {
            const float4 xv = *reinterpret_cast<const float4*>(&X[nd][k4]); // broadcast
            acc[nd] = fmaf(xv.w, wk3, fmaf(xv.z, wk2, fmaf(xv.y, wk1, fmaf(xv.x, wk0, acc[nd]))));
        }
    }

    const float wa = (isText ? w_adap[0] : w_adap[1]) * (1.0f / (float)NPG_);

    if (!isText) {
        #pragma unroll
        for (int nd = 0; nd < PNPB; ++nd)
            hl[nd][jc] = wa * (acc[nd] > 0.f ? acc[nd] : 0.f);
    }
    __syncthreads();
    if (isText) {
        #pragma unroll
        for (int nd = 0; nd < PNPB; ++nd) {
            const float ht = wa * (acc[nd] > 0.f ? acc[nd] : 0.f);
            h_comb[(size_t)(base + nd) * D_ + jc] = ht + hl[nd][jc];
        }
    }
}

// ---------------- Kernel C: per-graph readout + MLP, 4 blocks per graph split Wout ----------------
__global__ __launch_bounds__(256) void graph_kernel(
    const float* __restrict__ h_comb,   // [NN, D]
    const float* __restrict__ W1,       // [D, D]
    const float* __restrict__ b1,       // [D]
    const float* __restrict__ Wout,     // [D, OUT]
    const float* __restrict__ bout,     // [OUT]
    float*       __restrict__ out)      // [BG, OUT]
{
    __shared__ float fused[D_];
    __shared__ float hrow[D_];

    const int bx   = blockIdx.x;
    const int b    = bx >> 2;
    const int part = bx & 3;
    const int tid  = threadIdx.x;

    float acc = 0.f;
    const float* __restrict__ basep = h_comb + (size_t)b * NPG_ * D_ + tid;
    #pragma unroll 8
    for (int n = 0; n < NPG_; ++n) acc += basep[(size_t)n * D_];
    fused[tid] = acc;
    __syncthreads();

    float a1 = b1[tid];
    for (int d = 0; d < D_; ++d)
        a1 = fmaf(fused[d], W1[(size_t)d * D_ + tid], a1);
    hrow[tid] = a1 > 0.f ? a1 : 0.f;
    __syncthreads();

    const int j = part * 256 + tid;
    float o = bout[j];
    for (int d = 0; d < D_; ++d)
        o = fmaf(hrow[d], Wout[(size_t)d * OUT_ + j], o);
    out[(size_t)b * OUT_ + j] = o;
}

extern "C" void kernel_launch(void* const* d_in, const int* in_sizes, int n_in,
                              void* d_out, int out_size, void* d_ws, size_t ws_size,
                              hipStream_t stream) {
    const int*   text_ids  = (const int*)  d_in[0];
    const int*   label_ids = (const int*)  d_in[1];
    const int*   text_len  = (const int*)  d_in[2];
    const int*   label_len = (const int*)  d_in[3];
    const float* word_emb  = (const float*)d_in[4];
    const float* label_emb = (const float*)d_in[5];
    const float* Wg_text   = (const float*)d_in[6];
    const float* Wg_label  = (const float*)d_in[7];
    const float* w_adap    = (const float*)d_in[8];
    const float* W1        = (const float*)d_in[9];
    const float* b1        = (const float*)d_in[10];
    const float* Wout      = (const float*)d_in[11];
    const float* bout      = (const float*)d_in[12];

    // ws layout: [0, 4MB) text_out (reused as h_comb: row-disjoint per block), [4MB, 8MB) label_out
    float* text_out  = (float*)d_ws;
    float* label_out = text_out + (size_t)NN * D_;
    float* h_comb    = text_out;
    float* out       = (float*)d_out;

    gather_kernel<<<NN, 256, 0, stream>>>(
        text_ids, label_ids, text_len, label_len,
        word_emb, label_emb, text_out, label_out);

    proj_kernel<<<NN / PNPB, 512, 0, stream>>>(
        text_out, label_out, Wg_text, Wg_label, w_adap, h_comb);

    graph_kernel<<<BG * 4, 256, 0, stream>>>(
        h_comb, W1, b1, Wout, bout, out);
}

// Round 9
// 88.833 us; speedup vs baseline: 1.6667x; 1.2830x over previous
//
#include <hip/hip_runtime.h>

#define NN      4096   // total nodes
#define BG      64     // graphs
#define NPG_    64     // nodes per graph
#define LT_     128
#define LL_     32
#define D_      256
#define OUT_    1024

typedef __attribute__((ext_vector_type(8))) short bf16x8;   // 8 bf16 = 4 VGPR
typedef __attribute__((ext_vector_type(4))) float f32x4;

// split f32 into bf16 hi + bf16 lo (round-half-up on magnitude bits);
// v ~= hi + lo with representation error <= 2^-18 * |v|
__device__ __forceinline__ void split_bf16(float v, unsigned short& hi, unsigned short& lo) {
    union { float f; unsigned u; } a; a.f = v;
    const unsigned hu = (a.u + 0x8000u) & 0xFFFF0000u;
    union { unsigned u; float f; } h; h.u = hu;
    const float r = v - h.f;                  // exact
    union { float f; unsigned u; } b; b.f = r;
    hi = (unsigned short)(hu >> 16);
    lo = (unsigned short)(((b.u + 0x8000u) & 0xFFFF0000u) >> 16);
}

// ---------------- Kernel 0: pack W into MFMA B-fragment layout ----------------
// Wpk[mat][hl][nt(16)][ks(8)][lane(64)][e(8)] bf16: B-frag for 16x16x32 MFMA:
// lane = col(0..15) + 16*kchunk, elems = 8 consecutive k. 512 KB total.
__global__ __launch_bounds__(256) void convw_kernel(
    const float* __restrict__ Wg_text,
    const float* __restrict__ Wg_label,
    unsigned short* __restrict__ Wpk)
{
    const int b   = blockIdx.x;            // 256 blocks: mat(2) x nt(16) x ks(8)
    const int mat = b >> 7;
    const int nt  = (b >> 3) & 15;
    const int ks  = b & 7;
    const float* __restrict__ W = mat ? Wg_label : Wg_text;
    const int tid = threadIdx.x;

    #pragma unroll
    for (int r = 0; r < 2; ++r) {
        const int idx = tid + 256 * r;     // 0..511 = 32 k x 16 cols
        const int kl  = idx >> 4;          // local k within the 32-k step
        const int c16 = idx & 15;
        const int k   = ks * 32 + kl;
        const float v = W[(size_t)k * D_ + nt * 16 + c16];
        unsigned short h, l;
        split_bf16(v, h, l);
        const int lane = c16 + 16 * ((kl >> 3) & 3);
        const int e    = kl & 7;
        const size_t bh = ((((size_t)mat * 2 + 0) * 16 + nt) * 8 + ks) * 512 + lane * 8 + e;
        const size_t bl = ((((size_t)mat * 2 + 1) * 16 + nt) * 8 + ks) * 512 + lane * 8 + e;
        Wpk[bh] = h;
        Wpk[bl] = l;
    }
}

// ---------------- Kernel A: ragged gathers (proven 59us), bf16 hi/lo epilogue ----------------
__global__ __launch_bounds__(256) void gather_kernel(
    const int*   __restrict__ text_ids,
    const int*   __restrict__ label_ids,
    const int*   __restrict__ text_len,
    const int*   __restrict__ label_len,
    const float* __restrict__ word_emb,
    const float* __restrict__ label_emb,
    unsigned short* __restrict__ xh_t,   // [NN, D] bf16 hi of text_out
    unsigned short* __restrict__ xl_t,   // lo
    unsigned short* __restrict__ xh_l,   // label hi
    unsigned short* __restrict__ xl_l)   // label lo
{
    __shared__ int   sIds[LT_ + LL_];
    __shared__ float redT[4][D_];
    __shared__ float redL[4][D_];

    const int n    = blockIdx.x;
    const int tid  = threadIdx.x;
    const int wave = tid >> 6;
    const int lane = tid & 63;

    if (tid < LT_)               sIds[tid] = text_ids [(size_t)n * LT_ + tid];
    else if (tid < LT_ + LL_)    sIds[tid] = label_ids[(size_t)n * LL_ + (tid - LT_)];
    const int lt = text_len[n];
    const int ll = label_len[n];
    __syncthreads();

    float4 aT = make_float4(0.f, 0.f, 0.f, 0.f);
    float4 aL = make_float4(0.f, 0.f, 0.f, 0.f);

    {   // text partial sum: wave w takes l = w, w+4, ...
        const float* __restrict__ bp = word_emb + (size_t)lane * 4;
        #pragma unroll 8
        for (int l = wave; l < lt; l += 4) {
            const float4 v = *reinterpret_cast<const float4*>(bp + (size_t)sIds[l] * D_);
            aT.x += v.x; aT.y += v.y; aT.z += v.z; aT.w += v.w;
        }
    }
    {   // label partial sum
        const float* __restrict__ bp = label_emb + (size_t)lane * 4;
        #pragma unroll 8
        for (int l = wave; l < ll; l += 4) {
            const float4 v = *reinterpret_cast<const float4*>(bp + (size_t)sIds[LT_ + l] * D_);
            aL.x += v.x; aL.y += v.y; aL.z += v.z; aL.w += v.w;
        }
    }

    *reinterpret_cast<float4*>(&redT[wave][lane * 4]) = aT;
    *reinterpret_cast<float4*>(&redL[wave][lane * 4]) = aL;
    __syncthreads();

    const float t  = ((redT[0][tid] + redT[1][tid]) + (redT[2][tid] + redT[3][tid])) / (float)lt;
    const float lv =  (redL[0][tid] + redL[1][tid]) + (redL[2][tid] + redL[3][tid]);

    unsigned short h, l;
    const size_t o = (size_t)n * D_ + tid;
    split_bf16(t,  h, l);  xh_t[o] = h;  xl_t[o] = l;
    split_bf16(lv, h, l);  xh_l[o] = h;  xl_l[o] = l;
}

// ---------------- Kernel B: MFMA projection (bf16x2 split, 4 terms = f32-exact-ish) ----------
// 256 blocks x 512 thr (8 waves), 16 nodes/block. Wave w owns col-tiles {2w, 2w+1}.
// A-frags from XOR-swizzled LDS; B-frags from packed global (read once/block -> 128 MB L2).
__global__ __launch_bounds__(512) void proj_kernel(
    const unsigned short* __restrict__ xh_t,
    const unsigned short* __restrict__ xl_t,
    const unsigned short* __restrict__ xh_l,
    const unsigned short* __restrict__ xl_l,
    const unsigned short* __restrict__ Wpk,
    const float* __restrict__ w_adap,
    float*       __restrict__ h_comb)     // [NN, D]
{
    __shared__ __align__(16) short ldsX[4][16 * D_];   // 4 arrays x 16 nodes x 256 k, 32 KB

    const int tid  = threadIdx.x;
    const int wave = tid >> 6;
    const int lane = tid & 63;
    const int base = blockIdx.x * 16;

    // ---- stage x tiles: thread -> node nd = tid>>5, 16B-chunk ch = tid&31 ----
    {
        const int nd = tid >> 5, ch = tid & 31;
        const size_t g = (size_t)(base + nd) * D_ + ch * 8;
        const int d = nd * D_ + ((ch ^ (nd & 7)) * 8);     // XOR-swizzled slot
        *reinterpret_cast<int4*>(&ldsX[0][d]) = *reinterpret_cast<const int4*>(&xh_t[g]);
        *reinterpret_cast<int4*>(&ldsX[1][d]) = *reinterpret_cast<const int4*>(&xl_t[g]);
        *reinterpret_cast<int4*>(&ldsX[2][d]) = *reinterpret_cast<const int4*>(&xh_l[g]);
        *reinterpret_cast<int4*>(&ldsX[3][d]) = *reinterpret_cast<const int4*>(&xl_l[g]);
    }
    __syncthreads();

    const int nt0 = wave * 2;
    const int row = lane & 15;     // A row (node within tile)
    const int kc  = lane >> 4;     // k-chunk
    f32x4 accT[2] = {{0.f,0.f,0.f,0.f},{0.f,0.f,0.f,0.f}};
    f32x4 accL[2] = {{0.f,0.f,0.f,0.f},{0.f,0.f,0.f,0.f}};

    #pragma unroll
    for (int ks = 0; ks < 8; ++ks) {
        const int aidx = row * D_ + (((ks * 4 + kc) ^ (row & 7)) * 8);
        const bf16x8 ath  = *reinterpret_cast<const bf16x8*>(&ldsX[0][aidx]);
        const bf16x8 atl  = *reinterpret_cast<const bf16x8*>(&ldsX[1][aidx]);
        const bf16x8 alh  = *reinterpret_cast<const bf16x8*>(&ldsX[2][aidx]);
        const bf16x8 all_ = *reinterpret_cast<const bf16x8*>(&ldsX[3][aidx]);

        #pragma unroll
        for (int i = 0; i < 2; ++i) {
            const int nt = nt0 + i;
            const bf16x8 bth = *reinterpret_cast<const bf16x8*>(
                &Wpk[(((size_t)0 * 16 + nt) * 8 + ks) * 512 + lane * 8]);
            const bf16x8 btl = *reinterpret_cast<const bf16x8*>(
                &Wpk[(((size_t)1 * 16 + nt) * 8 + ks) * 512 + lane * 8]);
            const bf16x8 blh = *reinterpret_cast<const bf16x8*>(
                &Wpk[(((size_t)2 * 16 + nt) * 8 + ks) * 512 + lane * 8]);
            const bf16x8 bll = *reinterpret_cast<const bf16x8*>(
                &Wpk[(((size_t)3 * 16 + nt) * 8 + ks) * 512 + lane * 8]);

            accT[i] = __builtin_amdgcn_mfma_f32_16x16x32_bf16(ath, bth, accT[i], 0, 0, 0);
            accT[i] = __builtin_amdgcn_mfma_f32_16x16x32_bf16(ath, btl, accT[i], 0, 0, 0);
            accT[i] = __builtin_amdgcn_mfma_f32_16x16x32_bf16(atl, bth, accT[i], 0, 0, 0);
            accT[i] = __builtin_amdgcn_mfma_f32_16x16x32_bf16(atl, btl, accT[i], 0, 0, 0);

            accL[i] = __builtin_amdgcn_mfma_f32_16x16x32_bf16(alh, blh, accL[i], 0, 0, 0);
            accL[i] = __builtin_amdgcn_mfma_f32_16x16x32_bf16(alh, bll, accL[i], 0, 0, 0);
            accL[i] = __builtin_amdgcn_mfma_f32_16x16x32_bf16(all_, blh, accL[i], 0, 0, 0);
            accL[i] = __builtin_amdgcn_mfma_f32_16x16x32_bf16(all_, bll, accL[i], 0, 0, 0);
        }
    }

    // C/D layout (m89-verified): col = lane&15, row = (lane>>4)*4 + reg
    const float w0r = w_adap[0] * (1.0f / (float)NPG_);
    const float w1r = w_adap[1] * (1.0f / (float)NPG_);
    #pragma unroll
    for (int i = 0; i < 2; ++i) {
        #pragma unroll
        for (int r = 0; r < 4; ++r) {
            const int node = base + kc * 4 + r;
            const int col  = (nt0 + i) * 16 + row;
            const float ht = accT[i][r] > 0.f ? accT[i][r] : 0.f;
            const float hl = accL[i][r] > 0.f ? accL[i][r] : 0.f;
            h_comb[(size_t)node * D_ + col] = w0r * ht + w1r * hl;
        }
    }
}

// ---------------- Kernel C: per-graph readout + MLP, 4 blocks per graph split Wout ----------------
__global__ __launch_bounds__(256) void graph_kernel(
    const float* __restrict__ h_comb,   // [NN, D]
    const float* __restrict__ W1,       // [D, D]
    const float* __restrict__ b1,       // [D]
    const float* __restrict__ Wout,     // [D, OUT]
    const float* __restrict__ bout,     // [OUT]
    float*       __restrict__ out)      // [BG, OUT]
{
    __shared__ float fused[D_];
    __shared__ float hrow[D_];

    const int bx   = blockIdx.x;
    const int b    = bx >> 2;
    const int part = bx & 3;
    const int tid  = threadIdx.x;

    float acc = 0.f;
    const float* __restrict__ basep = h_comb + (size_t)b * NPG_ * D_ + tid;
    #pragma unroll 8
    for (int n = 0; n < NPG_; ++n) acc += basep[(size_t)n * D_];
    fused[tid] = acc;
    __syncthreads();

    float a1 = b1[tid];
    for (int d = 0; d < D_; ++d)
        a1 = fmaf(fused[d], W1[(size_t)d * D_ + tid], a1);
    hrow[tid] = a1 > 0.f ? a1 : 0.f;
    __syncthreads();

    const int j = part * 256 + tid;
    float o = bout[j];
    for (int d = 0; d < D_; ++d)
        o = fmaf(hrow[d], Wout[(size_t)d * OUT_ + j], o);
    out[(size_t)b * OUT_ + j] = o;
}

extern "C" void kernel_launch(void* const* d_in, const int* in_sizes, int n_in,
                              void* d_out, int out_size, void* d_ws, size_t ws_size,
                              hipStream_t stream) {
    const int*   text_ids  = (const int*)  d_in[0];
    const int*   label_ids = (const int*)  d_in[1];
    const int*   text_len  = (const int*)  d_in[2];
    const int*   label_len = (const int*)  d_in[3];
    const float* word_emb  = (const float*)d_in[4];
    const float* label_emb = (const float*)d_in[5];
    const float* Wg_text   = (const float*)d_in[6];
    const float* Wg_label  = (const float*)d_in[7];
    const float* w_adap    = (const float*)d_in[8];
    const float* W1        = (const float*)d_in[9];
    const float* b1        = (const float*)d_in[10];
    const float* Wout      = (const float*)d_in[11];
    const float* bout      = (const float*)d_in[12];

    // ws layout (byte offsets):
    //   [0,       4 MB)  h_comb  f32 [NN][D]
    //   [4..12 MB)       xh_t, xl_t, xh_l, xl_l  bf16 [NN][D] (2 MB each)
    //   [12 MB, +512 KB) Wpk packed bf16 B-fragments
    char* ws = (char*)d_ws;
    float*          h_comb = (float*)ws;
    unsigned short* xh_t   = (unsigned short*)(ws + (4  << 20));
    unsigned short* xl_t   = (unsigned short*)(ws + (6  << 20));
    unsigned short* xh_l   = (unsigned short*)(ws + (8  << 20));
    unsigned short* xl_l   = (unsigned short*)(ws + (10 << 20));
    unsigned short* Wpk    = (unsigned short*)(ws + (12 << 20));
    float*          out    = (float*)d_out;

    convw_kernel<<<256, 256, 0, stream>>>(Wg_text, Wg_label, Wpk);

    gather_kernel<<<NN, 256, 0, stream>>>(
        text_ids, label_ids, text_len, label_len,
        word_emb, label_emb, xh_t, xl_t, xh_l, xl_l);

    proj_kernel<<<NN / 16, 512, 0, stream>>>(
        xh_t, xl_t, xh_l, xl_l, Wpk, w_adap, h_comb);

    graph_kernel<<<BG * 4, 256, 0, stream>>>(
        h_comb, W1, b1, Wout, bout, out);
}

// Round 10
// 87.581 us; speedup vs baseline: 1.6905x; 1.0143x over previous
//
#include <hip/hip_runtime.h>

#define NN      4096   // total nodes
#define BG      64     // graphs
#define NPG_    64     // nodes per graph
#define LT_     128
#define LL_     32
#define D_      256
#define OUT_    1024

typedef __attribute__((ext_vector_type(8))) short bf16x8;   // 8 bf16 = 4 VGPR
typedef __attribute__((ext_vector_type(4))) float f32x4;

// split f32 into bf16 hi + bf16 lo; v ~= hi + lo, representation error <= 2^-18 * |v|
__device__ __forceinline__ void split_bf16(float v, unsigned short& hi, unsigned short& lo) {
    union { float f; unsigned u; } a; a.f = v;
    const unsigned hu = (a.u + 0x8000u) & 0xFFFF0000u;
    union { unsigned u; float f; } h; h.u = hu;
    const float r = v - h.f;                  // exact
    union { float f; unsigned u; } b; b.f = r;
    hi = (unsigned short)(hu >> 16);
    lo = (unsigned short)(((b.u + 0x8000u) & 0xFFFF0000u) >> 16);
}

// ---------------- Kernel 0: pack W into MFMA B-fragment layout ----------------
// Wpk[mat*2+hl][nt(16)][ks(8)][lane(64)][e(8)] bf16, 512 KB. (unchanged, proven)
__global__ __launch_bounds__(256) void convw_kernel(
    const float* __restrict__ Wg_text,
    const float* __restrict__ Wg_label,
    unsigned short* __restrict__ Wpk)
{
    const int b   = blockIdx.x;            // 256 blocks: mat(2) x nt(16) x ks(8)
    const int mat = b >> 7;
    const int nt  = (b >> 3) & 15;
    const int ks  = b & 7;
    const float* __restrict__ W = mat ? Wg_label : Wg_text;
    const int tid = threadIdx.x;

    #pragma unroll
    for (int r = 0; r < 2; ++r) {
        const int idx = tid + 256 * r;     // 0..511 = 32 k x 16 cols
        const int kl  = idx >> 4;          // local k within the 32-k step
        const int c16 = idx & 15;
        const int k   = ks * 32 + kl;
        const float v = W[(size_t)k * D_ + nt * 16 + c16];
        unsigned short h, l;
        split_bf16(v, h, l);
        const int lane = c16 + 16 * ((kl >> 3) & 3);
        const int e    = kl & 7;
        const size_t bh = ((((size_t)mat * 2 + 0) * 16 + nt) * 8 + ks) * 512 + lane * 8 + e;
        const size_t bl = ((((size_t)mat * 2 + 1) * 16 + nt) * 8 + ks) * 512 + lane * 8 + e;
        Wpk[bh] = h;
        Wpk[bl] = l;
    }
}

// ---------------- Kernel A: ragged gathers (proven 59us), bf16 hi/lo epilogue ----------------
__global__ __launch_bounds__(256) void gather_kernel(
    const int*   __restrict__ text_ids,
    const int*   __restrict__ label_ids,
    const int*   __restrict__ text_len,
    const int*   __restrict__ label_len,
    const float* __restrict__ word_emb,
    const float* __restrict__ label_emb,
    unsigned short* __restrict__ xh_t,   // [NN, D] bf16 hi of text_out
    unsigned short* __restrict__ xl_t,   // lo
    unsigned short* __restrict__ xh_l,   // label hi
    unsigned short* __restrict__ xl_l)   // label lo
{
    __shared__ int   sIds[LT_ + LL_];
    __shared__ float redT[4][D_];
    __shared__ float redL[4][D_];

    const int n    = blockIdx.x;
    const int tid  = threadIdx.x;
    const int wave = tid >> 6;
    const int lane = tid & 63;

    if (tid < LT_)               sIds[tid] = text_ids [(size_t)n * LT_ + tid];
    else if (tid < LT_ + LL_)    sIds[tid] = label_ids[(size_t)n * LL_ + (tid - LT_)];
    const int lt = text_len[n];
    const int ll = label_len[n];
    __syncthreads();

    float4 aT = make_float4(0.f, 0.f, 0.f, 0.f);
    float4 aL = make_float4(0.f, 0.f, 0.f, 0.f);

    {   // text partial sum: wave w takes l = w, w+4, ...
        const float* __restrict__ bp = word_emb + (size_t)lane * 4;
        #pragma unroll 8
        for (int l = wave; l < lt; l += 4) {
            const float4 v = *reinterpret_cast<const float4*>(bp + (size_t)sIds[l] * D_);
            aT.x += v.x; aT.y += v.y; aT.z += v.z; aT.w += v.w;
        }
    }
    {   // label partial sum
        const float* __restrict__ bp = label_emb + (size_t)lane * 4;
        #pragma unroll 8
        for (int l = wave; l < ll; l += 4) {
            const float4 v = *reinterpret_cast<const float4*>(bp + (size_t)sIds[LT_ + l] * D_);
            aL.x += v.x; aL.y += v.y; aL.z += v.z; aL.w += v.w;
        }
    }

    *reinterpret_cast<float4*>(&redT[wave][lane * 4]) = aT;
    *reinterpret_cast<float4*>(&redL[wave][lane * 4]) = aL;
    __syncthreads();

    const float t  = ((redT[0][tid] + redT[1][tid]) + (redT[2][tid] + redT[3][tid])) / (float)lt;
    const float lv =  (redL[0][tid] + redL[1][tid]) + (redL[2][tid] + redL[3][tid]);

    unsigned short h, l;
    const size_t o = (size_t)n * D_ + tid;
    split_bf16(t,  h, l);  xh_t[o] = h;  xl_t[o] = l;
    split_bf16(lv, h, l);  xh_l[o] = h;  xl_l[o] = l;
}

// ---------------- Kernel B: MFMA projection, col-split for occupancy ----------
// 512 blocks x 512 thr: block = (node-tile nt16) x (col half). 2 blocks/CU,
// 16 waves/CU. Wave w owns col-tile nt = chalf*8 + w. 3-term bf16x2 split
// (hh + hl + lh; lo*lo dropped, err ~2^-18). W read once per col-half ->
// 128 MB L2 total. A-frags from XOR-swizzled LDS.
__global__ __launch_bounds__(512, 4) void proj_kernel(
    const unsigned short* __restrict__ xh_t,
    const unsigned short* __restrict__ xl_t,
    const unsigned short* __restrict__ xh_l,
    const unsigned short* __restrict__ xl_l,
    const unsigned short* __restrict__ Wpk,
    const float* __restrict__ w_adap,
    float*       __restrict__ h_comb)     // [NN, D]
{
    __shared__ __align__(16) short ldsX[4][16 * D_];   // 32 KB

    const int tid   = threadIdx.x;
    const int wave  = tid >> 6;
    const int lane  = tid & 63;
    const int ntile = blockIdx.x >> 1;
    const int chalf = blockIdx.x & 1;
    const int base  = ntile * 16;

    // ---- stage x tiles: thread -> node nd = tid>>5, 16B-chunk ch = tid&31 ----
    {
        const int nd = tid >> 5, ch = tid & 31;
        const size_t g = (size_t)(base + nd) * D_ + ch * 8;
        const int d = nd * D_ + ((ch ^ (nd & 7)) * 8);     // XOR-swizzled slot
        *reinterpret_cast<int4*>(&ldsX[0][d]) = *reinterpret_cast<const int4*>(&xh_t[g]);
        *reinterpret_cast<int4*>(&ldsX[1][d]) = *reinterpret_cast<const int4*>(&xl_t[g]);
        *reinterpret_cast<int4*>(&ldsX[2][d]) = *reinterpret_cast<const int4*>(&xh_l[g]);
        *reinterpret_cast<int4*>(&ldsX[3][d]) = *reinterpret_cast<const int4*>(&xl_l[g]);
    }
    __syncthreads();

    const int nt  = chalf * 8 + wave;   // owned col-tile
    const int row = lane & 15;          // A row (node within tile)
    const int kc  = lane >> 4;          // k-chunk
    f32x4 accT = {0.f, 0.f, 0.f, 0.f};
    f32x4 accL = {0.f, 0.f, 0.f, 0.f};

    #pragma unroll
    for (int ks = 0; ks < 8; ++ks) {
        const int aidx = row * D_ + (((ks * 4 + kc) ^ (row & 7)) * 8);
        const bf16x8 ath  = *reinterpret_cast<const bf16x8*>(&ldsX[0][aidx]);
        const bf16x8 atl  = *reinterpret_cast<const bf16x8*>(&ldsX[1][aidx]);
        const bf16x8 alh  = *reinterpret_cast<const bf16x8*>(&ldsX[2][aidx]);
        const bf16x8 all_ = *reinterpret_cast<const bf16x8*>(&ldsX[3][aidx]);

        const bf16x8 bth = *reinterpret_cast<const bf16x8*>(
            &Wpk[(((size_t)0 * 16 + nt) * 8 + ks) * 512 + lane * 8]);
        const bf16x8 btl = *reinterpret_cast<const bf16x8*>(
            &Wpk[(((size_t)1 * 16 + nt) * 8 + ks) * 512 + lane * 8]);
        const bf16x8 blh = *reinterpret_cast<const bf16x8*>(
            &Wpk[(((size_t)2 * 16 + nt) * 8 + ks) * 512 + lane * 8]);
        const bf16x8 bll = *reinterpret_cast<const bf16x8*>(
            &Wpk[(((size_t)3 * 16 + nt) * 8 + ks) * 512 + lane * 8]);

        accT = __builtin_amdgcn_mfma_f32_16x16x32_bf16(ath, bth, accT, 0, 0, 0);
        accT = __builtin_amdgcn_mfma_f32_16x16x32_bf16(ath, btl, accT, 0, 0, 0);
        accT = __builtin_amdgcn_mfma_f32_16x16x32_bf16(atl, bth, accT, 0, 0, 0);

        accL = __builtin_amdgcn_mfma_f32_16x16x32_bf16(alh, blh, accL, 0, 0, 0);
        accL = __builtin_amdgcn_mfma_f32_16x16x32_bf16(alh, bll, accL, 0, 0, 0);
        accL = __builtin_amdgcn_mfma_f32_16x16x32_bf16(all_, blh, accL, 0, 0, 0);
    }

    // C/D layout (m89-verified): col = lane&15, row = (lane>>4)*4 + reg
    const float w0r = w_adap[0] * (1.0f / (float)NPG_);
    const float w1r = w_adap[1] * (1.0f / (float)NPG_);
    #pragma unroll
    for (int r = 0; r < 4; ++r) {
        const int node = base + kc * 4 + r;
        const int col  = nt * 16 + row;
        const float ht = accT[r] > 0.f ? accT[r] : 0.f;
        const float hl = accL[r] > 0.f ? accL[r] : 0.f;
        h_comb[(size_t)node * D_ + col] = w0r * ht + w1r * hl;
    }
}

// ---------------- Kernel C: per-graph readout + MLP, 4 blocks per graph split Wout ----------------
__global__ __launch_bounds__(256) void graph_kernel(
    const float* __restrict__ h_comb,   // [NN, D]
    const float* __restrict__ W1,       // [D, D]
    const float* __restrict__ b1,       // [D]
    const float* __restrict__ Wout,     // [D, OUT]
    const float* __restrict__ bout,     // [OUT]
    float*       __restrict__ out)      // [BG, OUT]
{
    __shared__ float fused[D_];
    __shared__ float hrow[D_];

    const int bx   = blockIdx.x;
    const int b    = bx >> 2;
    const int part = bx & 3;
    const int tid  = threadIdx.x;

    float acc = 0.f;
    const float* __restrict__ basep = h_comb + (size_t)b * NPG_ * D_ + tid;
    #pragma unroll 8
    for (int n = 0; n < NPG_; ++n) acc += basep[(size_t)n * D_];
    fused[tid] = acc;
    __syncthreads();

    float a1 = b1[tid];
    for (int d = 0; d < D_; ++d)
        a1 = fmaf(fused[d], W1[(size_t)d * D_ + tid], a1);
    hrow[tid] = a1 > 0.f ? a1 : 0.f;
    __syncthreads();

    const int j = part * 256 + tid;
    float o = bout[j];
    for (int d = 0; d < D_; ++d)
        o = fmaf(hrow[d], Wout[(size_t)d * OUT_ + j], o);
    out[(size_t)b * OUT_ + j] = o;
}

extern "C" void kernel_launch(void* const* d_in, const int* in_sizes, int n_in,
                              void* d_out, int out_size, void* d_ws, size_t ws_size,
                              hipStream_t stream) {
    const int*   text_ids  = (const int*)  d_in[0];
    const int*   label_ids = (const int*)  d_in[1];
    const int*   text_len  = (const int*)  d_in[2];
    const int*   label_len = (const int*)  d_in[3];
    const float* word_emb  = (const float*)d_in[4];
    const float* label_emb = (const float*)d_in[5];
    const float* Wg_text   = (const float*)d_in[6];
    const float* Wg_label  = (const float*)d_in[7];
    const float* w_adap    = (const float*)d_in[8];
    const float* W1        = (const float*)d_in[9];
    const float* b1        = (const float*)d_in[10];
    const float* Wout      = (const float*)d_in[11];
    const float* bout      = (const float*)d_in[12];

    // ws layout (byte offsets):
    //   [0,       4 MB)  h_comb  f32 [NN][D]
    //   [4..12 MB)       xh_t, xl_t, xh_l, xl_l  bf16 [NN][D] (2 MB each)
    //   [12 MB, +512 KB) Wpk packed bf16 B-fragments
    char* ws = (char*)d_ws;
    float*          h_comb = (float*)ws;
    unsigned short* xh_t   = (unsigned short*)(ws + (4  << 20));
    unsigned short* xl_t   = (unsigned short*)(ws + (6  << 20));
    unsigned short* xh_l   = (unsigned short*)(ws + (8  << 20));
    unsigned short* xl_l   = (unsigned short*)(ws + (10 << 20));
    unsigned short* Wpk    = (unsigned short*)(ws + (12 << 20));
    float*          out    = (float*)d_out;

    convw_kernel<<<256, 256, 0, stream>>>(Wg_text, Wg_label, Wpk);

    gather_kernel<<<NN, 256, 0, stream>>>(
        text_ids, label_ids, text_len, label_len,
        word_emb, label_emb, xh_t, xl_t, xh_l, xl_l);

    proj_kernel<<<NN / 16 * 2, 512, 0, stream>>>(
        xh_t, xl_t, xh_l, xl_l, Wpk, w_adap, h_comb);

    graph_kernel<<<BG * 4, 256, 0, stream>>>(
        h_comb, W1, b1, Wout, bout, out);
}

// Round 11
// 84.697 us; speedup vs baseline: 1.7481x; 1.0341x over previous
//
#include <hip/hip_runtime.h>

#define NN      4096   // total nodes
#define BG      64     // graphs
#define NPG_    64     // nodes per graph
#define LT_     128
#define LL_     32
#define D_      256
#define OUT_    1024

typedef __attribute__((ext_vector_type(8))) short bf16x8;   // 8 bf16 = 4 VGPR
typedef __attribute__((ext_vector_type(4))) float f32x4;

// split f32 into bf16 hi + bf16 lo; v ~= hi + lo, representation error <= 2^-18 * |v|
__device__ __forceinline__ void split_bf16(float v, unsigned short& hi, unsigned short& lo) {
    union { float f; unsigned u; } a; a.f = v;
    const unsigned hu = (a.u + 0x8000u) & 0xFFFF0000u;
    union { unsigned u; float f; } h; h.u = hu;
    const float r = v - h.f;                  // exact
    union { float f; unsigned u; } b; b.f = r;
    hi = (unsigned short)(hu >> 16);
    lo = (unsigned short)(((b.u + 0x8000u) & 0xFFFF0000u) >> 16);
}

// ---------------- Kernel A: ragged gathers (proven ~60us) + convw piggyback ----------------
// Blocks [0, NN): per-node gather with bf16 hi/lo epilogue.
// Blocks [NN, NN+256): pack W into MFMA B-fragment layout
//   Wpk[nt(16)][ks(8)][plane(4: t-hi,t-lo,l-hi,l-lo)][lane(64)][e(8)] bf16, 512 KB.
__global__ __launch_bounds__(256) void gather_kernel(
    const int*   __restrict__ text_ids,
    const int*   __restrict__ label_ids,
    const int*   __restrict__ text_len,
    const int*   __restrict__ label_len,
    const float* __restrict__ word_emb,
    const float* __restrict__ label_emb,
    const float* __restrict__ Wg_text,
    const float* __restrict__ Wg_label,
    unsigned short* __restrict__ Wpk,
    unsigned short* __restrict__ xh_t,   // [NN, D] bf16 hi of text_out
    unsigned short* __restrict__ xl_t,   // lo
    unsigned short* __restrict__ xh_l,   // label hi
    unsigned short* __restrict__ xl_l)   // label lo
{
    const int tid  = threadIdx.x;

    // ---- convw role ----
    if (blockIdx.x >= NN) {
        const int b   = blockIdx.x - NN;   // 256 blocks: mat(2) x nt(16) x ks(8)
        const int mat = b >> 7;
        const int nt  = (b >> 3) & 15;
        const int ks  = b & 7;
        const float* __restrict__ W = mat ? Wg_label : Wg_text;
        #pragma unroll
        for (int r = 0; r < 2; ++r) {
            const int idx = tid + 256 * r;     // 0..511 = 32 k x 16 cols
            const int kl  = idx >> 4;          // local k within the 32-k step
            const int c16 = idx & 15;
            const int k   = ks * 32 + kl;
            const float v = W[(size_t)k * D_ + nt * 16 + c16];
            unsigned short h, l;
            split_bf16(v, h, l);
            const int lane = c16 + 16 * ((kl >> 3) & 3);
            const int e    = kl & 7;
            const size_t pb = (((size_t)nt * 8 + ks) * 4 + mat * 2) * 512 + lane * 8 + e;
            Wpk[pb]       = h;     // plane mat*2+0 (hi)
            Wpk[pb + 512] = l;     // plane mat*2+1 (lo)
        }
        return;
    }

    // ---- gather role ----
    __shared__ int   sIds[LT_ + LL_];
    __shared__ float redT[4][D_];
    __shared__ float redL[4][D_];

    const int n    = blockIdx.x;
    const int wave = tid >> 6;
    const int lane = tid & 63;

    if (tid < LT_)               sIds[tid] = text_ids [(size_t)n * LT_ + tid];
    else if (tid < LT_ + LL_)    sIds[tid] = label_ids[(size_t)n * LL_ + (tid - LT_)];
    const int lt = text_len[n];
    const int ll = label_len[n];
    __syncthreads();

    float4 aT = make_float4(0.f, 0.f, 0.f, 0.f);
    float4 aL = make_float4(0.f, 0.f, 0.f, 0.f);

    {   // text partial sum: wave w takes l = w, w+4, ...
        const float* __restrict__ bp = word_emb + (size_t)lane * 4;
        #pragma unroll 8
        for (int l = wave; l < lt; l += 4) {
            const float4 v = *reinterpret_cast<const float4*>(bp + (size_t)sIds[l] * D_);
            aT.x += v.x; aT.y += v.y; aT.z += v.z; aT.w += v.w;
        }
    }
    {   // label partial sum
        const float* __restrict__ bp = label_emb + (size_t)lane * 4;
        #pragma unroll 8
        for (int l = wave; l < ll; l += 4) {
            const float4 v = *reinterpret_cast<const float4*>(bp + (size_t)sIds[LT_ + l] * D_);
            aL.x += v.x; aL.y += v.y; aL.z += v.z; aL.w += v.w;
        }
    }

    *reinterpret_cast<float4*>(&redT[wave][lane * 4]) = aT;
    *reinterpret_cast<float4*>(&redL[wave][lane * 4]) = aL;
    __syncthreads();

    const float t  = ((redT[0][tid] + redT[1][tid]) + (redT[2][tid] + redT[3][tid])) / (float)lt;
    const float lv =  (redL[0][tid] + redL[1][tid]) + (redL[2][tid] + redL[3][tid]);

    unsigned short h, l;
    const size_t o = (size_t)n * D_ + tid;
    split_bf16(t,  h, l);  xh_t[o] = h;  xl_t[o] = l;
    split_bf16(lv, h, l);  xh_l[o] = h;  xl_l[o] = l;
}

// ---------------- Kernel B: MFMA projection, 4-wave blocks + 2-stage pipeline ----------
// 1024 blocks x 256 thr: block = (node-tile(256), col-quarter(4)). Wave w owns
// col-tile nt = cq*4 + w -> 4 blocks/CU, 16 waves/CU, independent MFMA phases.
// 3-term bf16x2 split (hh + hl + lh). B-frags of one (nt,ks) are contiguous (4KB).
__global__ __launch_bounds__(256, 4) void proj_kernel(
    const unsigned short* __restrict__ xh_t,
    const unsigned short* __restrict__ xl_t,
    const unsigned short* __restrict__ xh_l,
    const unsigned short* __restrict__ xl_l,
    const unsigned short* __restrict__ Wpk,
    const float* __restrict__ w_adap,
    float*       __restrict__ h_comb)     // [NN, D]
{
    __shared__ __align__(16) short ldsX[4][16 * D_];   // 32 KB

    const int tid   = threadIdx.x;
    const int wave  = tid >> 6;
    const int lane  = tid & 63;
    const int ntile = blockIdx.x >> 2;
    const int cq    = blockIdx.x & 3;
    const int base  = ntile * 16;

    // ---- stage x tiles (coalesced int4, XOR-swizzled slots) ----
    #pragma unroll
    for (int r = 0; r < 2; ++r) {
        const int idx = tid + 256 * r;     // 0..511
        const int nd  = idx >> 5, ch = idx & 31;
        const size_t g = (size_t)(base + nd) * D_ + ch * 8;
        const int d = nd * D_ + ((ch ^ (nd & 7)) * 8);
        *reinterpret_cast<int4*>(&ldsX[0][d]) = *reinterpret_cast<const int4*>(&xh_t[g]);
        *reinterpret_cast<int4*>(&ldsX[1][d]) = *reinterpret_cast<const int4*>(&xl_t[g]);
        *reinterpret_cast<int4*>(&ldsX[2][d]) = *reinterpret_cast<const int4*>(&xh_l[g]);
        *reinterpret_cast<int4*>(&ldsX[3][d]) = *reinterpret_cast<const int4*>(&xl_l[g]);
    }
    __syncthreads();

    const int nt  = cq * 4 + wave;      // owned col-tile
    const int row = lane & 15;          // A row (node within tile)
    const int kc  = lane >> 4;          // k-chunk
    const unsigned short* __restrict__ WpB = Wpk + ((size_t)nt * 8) * 4 * 512 + lane * 8;

    f32x4 accT = {0.f, 0.f, 0.f, 0.f};
    f32x4 accL = {0.f, 0.f, 0.f, 0.f};

    bf16x8 cA0, cA1, cA2, cA3, cB0, cB1, cB2, cB3;
    bf16x8 nA0, nA1, nA2, nA3, nB0, nB1, nB2, nB3;

    // prologue: load ks=0
    {
        const int aidx = row * D_ + ((kc ^ (row & 7)) * 8);
        cA0 = *reinterpret_cast<const bf16x8*>(&ldsX[0][aidx]);
        cA1 = *reinterpret_cast<const bf16x8*>(&ldsX[1][aidx]);
        cA2 = *reinterpret_cast<const bf16x8*>(&ldsX[2][aidx]);
        cA3 = *reinterpret_cast<const bf16x8*>(&ldsX[3][aidx]);
        const unsigned short* p = WpB;
        cB0 = *reinterpret_cast<const bf16x8*>(p);
        cB1 = *reinterpret_cast<const bf16x8*>(p + 512);
        cB2 = *reinterpret_cast<const bf16x8*>(p + 1024);
        cB3 = *reinterpret_cast<const bf16x8*>(p + 1536);
    }

    #pragma unroll
    for (int ks = 0; ks < 8; ++ks) {
        if (ks < 7) {   // prefetch ks+1 under current MFMAs
            const int aidx = row * D_ + ((((ks + 1) * 4 + kc) ^ (row & 7)) * 8);
            nA0 = *reinterpret_cast<const bf16x8*>(&ldsX[0][aidx]);
            nA1 = *reinterpret_cast<const bf16x8*>(&ldsX[1][aidx]);
            nA2 = *reinterpret_cast<const bf16x8*>(&ldsX[2][aidx]);
            nA3 = *reinterpret_cast<const bf16x8*>(&ldsX[3][aidx]);
            const unsigned short* p = WpB + (size_t)(ks + 1) * 2048;
            nB0 = *reinterpret_cast<const bf16x8*>(p);
            nB1 = *reinterpret_cast<const bf16x8*>(p + 512);
            nB2 = *reinterpret_cast<const bf16x8*>(p + 1024);
            nB3 = *reinterpret_cast<const bf16x8*>(p + 1536);
        }

        accT = __builtin_amdgcn_mfma_f32_16x16x32_bf16(cA0, cB0, accT, 0, 0, 0);
        accT = __builtin_amdgcn_mfma_f32_16x16x32_bf16(cA0, cB1, accT, 0, 0, 0);
        accT = __builtin_amdgcn_mfma_f32_16x16x32_bf16(cA1, cB0, accT, 0, 0, 0);
        accL = __builtin_amdgcn_mfma_f32_16x16x32_bf16(cA2, cB2, accL, 0, 0, 0);
        accL = __builtin_amdgcn_mfma_f32_16x16x32_bf16(cA2, cB3, accL, 0, 0, 0);
        accL = __builtin_amdgcn_mfma_f32_16x16x32_bf16(cA3, cB2, accL, 0, 0, 0);

        cA0 = nA0; cA1 = nA1; cA2 = nA2; cA3 = nA3;
        cB0 = nB0; cB1 = nB1; cB2 = nB2; cB3 = nB3;
    }

    // C/D layout (m89-verified): col = lane&15, row = (lane>>4)*4 + reg
    const float w0r = w_adap[0] * (1.0f / (float)NPG_);
    const float w1r = w_adap[1] * (1.0f / (float)NPG_);
    #pragma unroll
    for (int r = 0; r < 4; ++r) {
        const int node = base + kc * 4 + r;
        const int col  = nt * 16 + row;
        const float ht = accT[r] > 0.f ? accT[r] : 0.f;
        const float hl = accL[r] > 0.f ? accL[r] : 0.f;
        h_comb[(size_t)node * D_ + col] = w0r * ht + w1r * hl;
    }
}

// ---------------- Kernel C: per-graph readout + MLP, 4 blocks per graph split Wout ----------------
__global__ __launch_bounds__(256) void graph_kernel(
    const float* __restrict__ h_comb,   // [NN, D]
    const float* __restrict__ W1,       // [D, D]
    const float* __restrict__ b1,       // [D]
    const float* __restrict__ Wout,     // [D, OUT]
    const float* __restrict__ bout,     // [OUT]
    float*       __restrict__ out)      // [BG, OUT]
{
    __shared__ float fused[D_];
    __shared__ float hrow[D_];

    const int bx   = blockIdx.x;
    const int b    = bx >> 2;
    const int part = bx & 3;
    const int tid  = threadIdx.x;

    float acc = 0.f;
    const float* __restrict__ basep = h_comb + (size_t)b * NPG_ * D_ + tid;
    #pragma unroll 8
    for (int n = 0; n < NPG_; ++n) acc += basep[(size_t)n * D_];
    fused[tid] = acc;
    __syncthreads();

    // h = relu(fused @ W1 + b1), 4 partial chains for ILP (fixed order)
    {
        float s0 = 0.f, s1 = 0.f, s2 = 0.f, s3 = 0.f;
        const float* __restrict__ wp = W1 + tid;
        for (int d = 0; d < D_; d += 4) {
            s0 = fmaf(fused[d + 0], wp[(size_t)(d + 0) * D_], s0);
            s1 = fmaf(fused[d + 1], wp[(size_t)(d + 1) * D_], s1);
            s2 = fmaf(fused[d + 2], wp[(size_t)(d + 2) * D_], s2);
            s3 = fmaf(fused[d + 3], wp[(size_t)(d + 3) * D_], s3);
        }
        const float a1 = b1[tid] + ((s0 + s1) + (s2 + s3));
        hrow[tid] = a1 > 0.f ? a1 : 0.f;
    }
    __syncthreads();

    // out column j = part*256 + tid, 4 partial chains
    const int j = part * 256 + tid;
    {
        float s0 = 0.f, s1 = 0.f, s2 = 0.f, s3 = 0.f;
        const float* __restrict__ wp = Wout + j;
        for (int d = 0; d < D_; d += 4) {
            s0 = fmaf(hrow[d + 0], wp[(size_t)(d + 0) * OUT_], s0);
            s1 = fmaf(hrow[d + 1], wp[(size_t)(d + 1) * OUT_], s1);
            s2 = fmaf(hrow[d + 2], wp[(size_t)(d + 2) * OUT_], s2);
            s3 = fmaf(hrow[d + 3], wp[(size_t)(d + 3) * OUT_], s3);
        }
        out[(size_t)b * OUT_ + j] = bout[j] + ((s0 + s1) + (s2 + s3));
    }
}

extern "C" void kernel_launch(void* const* d_in, const int* in_sizes, int n_in,
                              void* d_out, int out_size, void* d_ws, size_t ws_size,
                              hipStream_t stream) {
    const int*   text_ids  = (const int*)  d_in[0];
    const int*   label_ids = (const int*)  d_in[1];
    const int*   text_len  = (const int*)  d_in[2];
    const int*   label_len = (const int*)  d_in[3];
    const float* word_emb  = (const float*)d_in[4];
    const float* label_emb = (const float*)d_in[5];
    const float* Wg_text   = (const float*)d_in[6];
    const float* Wg_label  = (const float*)d_in[7];
    const float* w_adap    = (const float*)d_in[8];
    const float* W1        = (const float*)d_in[9];
    const float* b1        = (const float*)d_in[10];
    const float* Wout      = (const float*)d_in[11];
    const float* bout      = (const float*)d_in[12];

    // ws layout (byte offsets):
    //   [0,       4 MB)  h_comb  f32 [NN][D]
    //   [4..12 MB)       xh_t, xl_t, xh_l, xl_l  bf16 [NN][D] (2 MB each)
    //   [12 MB, +512 KB) Wpk packed bf16 B-fragments
    char* ws = (char*)d_ws;
    float*          h_comb = (float*)ws;
    unsigned short* xh_t   = (unsigned short*)(ws + (4  << 20));
    unsigned short* xl_t   = (unsigned short*)(ws + (6  << 20));
    unsigned short* xh_l   = (unsigned short*)(ws + (8  << 20));
    unsigned short* xl_l   = (unsigned short*)(ws + (10 << 20));
    unsigned short* Wpk    = (unsigned short*)(ws + (12 << 20));
    float*          out    = (float*)d_out;

    gather_kernel<<<NN + 256, 256, 0, stream>>>(
        text_ids, label_ids, text_len, label_len,
        word_emb, label_emb, Wg_text, Wg_label, Wpk,
        xh_t, xl_t, xh_l, xl_l);

    proj_kernel<<<NN / 16 * 4, 256, 0, stream>>>(
        xh_t, xl_t, xh_l, xl_l, Wpk, w_adap, h_comb);

    graph_kernel<<<BG * 4, 256, 0, stream>>>(
        h_comb, W1, b1, Wout, bout, out);
}

// Round 12
// 75.410 us; speedup vs baseline: 1.9633x; 1.1232x over previous
//
#include <hip/hip_runtime.h>

#define NN      4096   // total nodes
#define BG      64     // graphs
#define NPG_    64     // nodes per graph
#define LT_     128
#define LL_     32
#define D_      256
#define OUT_    1024
#define VOCAB_  50000

typedef __attribute__((ext_vector_type(8))) short bf16x8;   // 8 bf16 = 4 VGPR
typedef __attribute__((ext_vector_type(4))) float f32x4;

__device__ __forceinline__ unsigned short f2bf_rne(float f) {
    union { float f; unsigned u; } a; a.f = f;
    const unsigned r = a.u + 0x7FFFu + ((a.u >> 16) & 1u);
    return (unsigned short)(r >> 16);
}
__device__ __forceinline__ float bf2f(unsigned short h) {
    union { unsigned u; float f; } a; a.u = ((unsigned)h) << 16;
    return a.f;
}
// split f32 into bf16 hi + lo; v ~= hi + lo, err <= 2^-18 |v| (W pack only)
__device__ __forceinline__ void split_bf16(float v, unsigned short& hi, unsigned short& lo) {
    union { float f; unsigned u; } a; a.f = v;
    const unsigned hu = (a.u + 0x8000u) & 0xFFFF0000u;
    union { unsigned u; float f; } h; h.u = hu;
    const float r = v - h.f;                  // exact
    union { float f; unsigned u; } b; b.f = r;
    hi = (unsigned short)(hu >> 16);
    lo = (unsigned short)(((b.u + 0x8000u) & 0xFFFF0000u) >> 16);
}

// ---------------- Kernel 0: word_emb -> bf16 table  +  W pack ----------------
// Blocks [0, convBlocks): grid-stride RNE conversion of word_emb (12.8M f32).
// Blocks [convBlocks, +256): pack W into Wpk[nt(16)][ks(8)][plane(4)][lane(64)][e(8)].
__global__ __launch_bounds__(256) void prep_kernel(
    const float* __restrict__ word_emb,
    const float* __restrict__ Wg_text,
    const float* __restrict__ Wg_label,
    const int convBlocks,
    unsigned short* __restrict__ wtab,
    unsigned short* __restrict__ Wpk)
{
    const int tid = threadIdx.x;
    if (blockIdx.x < convBlocks) {
        const int total4 = VOCAB_ * D_ / 4;          // 3,200,000 float4s
        const int stride = convBlocks * 256;
        for (int i = blockIdx.x * 256 + tid; i < total4; i += stride) {
            const float4 v = *reinterpret_cast<const float4*>(word_emb + (size_t)i * 4);
            ushort4 o;
            o.x = f2bf_rne(v.x); o.y = f2bf_rne(v.y);
            o.z = f2bf_rne(v.z); o.w = f2bf_rne(v.w);
            *reinterpret_cast<ushort4*>(wtab + (size_t)i * 4) = o;
        }
        return;
    }
    const int b   = blockIdx.x - convBlocks;   // 256 blocks: mat(2) x nt(16) x ks(8)
    const int mat = b >> 7;
    const int nt  = (b >> 3) & 15;
    const int ks  = b & 7;
    const float* __restrict__ W = mat ? Wg_label : Wg_text;
    #pragma unroll
    for (int r = 0; r < 2; ++r) {
        const int idx = tid + 256 * r;     // 0..511 = 32 k x 16 cols
        const int kl  = idx >> 4;
        const int c16 = idx & 15;
        const int k   = ks * 32 + kl;
        const float v = W[(size_t)k * D_ + nt * 16 + c16];
        unsigned short h, l;
        split_bf16(v, h, l);
        const int lane = c16 + 16 * ((kl >> 3) & 3);
        const int e    = kl & 7;
        const size_t pb = (((size_t)nt * 8 + ks) * 4 + mat * 2) * 512 + lane * 8 + e;
        Wpk[pb]       = h;     // plane mat*2+0 (hi)
        Wpk[pb + 512] = l;     // plane mat*2+1 (lo)
    }
}

// ---------------- Kernel A: ragged gathers -> single-bf16 x ----------------
// BF16TAB: text rows from bf16 table, 16B/lane = 8 cols, lane-halves take
// different rows -> 8 sub-streams. Label from f32 table (4-way float4, as proven).
template<bool BF16TAB>
__global__ __launch_bounds__(256) void gather_kernel(
    const int*   __restrict__ text_ids,
    const int*   __restrict__ label_ids,
    const int*   __restrict__ text_len,
    const int*   __restrict__ label_len,
    const float* __restrict__ word_emb,
    const unsigned short* __restrict__ wtab,
    const float* __restrict__ label_emb,
    unsigned short* __restrict__ xb_t,   // [NN, D] bf16
    unsigned short* __restrict__ xb_l)   // [NN, D] bf16
{
    __shared__ int   sIds[LT_ + LL_];
    __shared__ float red[8][D_];         // 8 KB, reused text then label

    const int n    = blockIdx.x;
    const int tid  = threadIdx.x;
    const int wave = tid >> 6;
    const int lane = tid & 63;

    if (tid < LT_)               sIds[tid] = text_ids [(size_t)n * LT_ + tid];
    else if (tid < LT_ + LL_)    sIds[tid] = label_ids[(size_t)n * LL_ + (tid - LT_)];
    const int lt = text_len[n];
    const int ll = label_len[n];
    __syncthreads();

    // ---- text gather ----
    float ta[8];
    float4 aT4 = make_float4(0.f, 0.f, 0.f, 0.f);
    if (BF16TAB) {
        #pragma unroll
        for (int j = 0; j < 8; ++j) ta[j] = 0.f;
        const int h  = lane >> 5;
        const int cg = lane & 31;
        const int s  = wave * 2 + h;               // sub-stream 0..7
        const unsigned short* __restrict__ bp = wtab + cg * 8;
        #pragma unroll 4
        for (int l = s; l < lt; l += 8) {
            const bf16x8 v = *reinterpret_cast<const bf16x8*>(bp + (size_t)sIds[l] * D_);
            #pragma unroll
            for (int j = 0; j < 8; ++j) ta[j] += bf2f((unsigned short)v[j]);
        }
    } else {
        const float* __restrict__ bp = word_emb + (size_t)lane * 4;
        #pragma unroll 8
        for (int l = wave; l < lt; l += 4) {
            const float4 v = *reinterpret_cast<const float4*>(bp + (size_t)sIds[l] * D_);
            aT4.x += v.x; aT4.y += v.y; aT4.z += v.z; aT4.w += v.w;
        }
    }

    // ---- label gather (f32, 4-way) ----
    float4 aL = make_float4(0.f, 0.f, 0.f, 0.f);
    {
        const float* __restrict__ bp = label_emb + (size_t)lane * 4;
        #pragma unroll 8
        for (int l = wave; l < ll; l += 4) {
            const float4 v = *reinterpret_cast<const float4*>(bp + (size_t)sIds[LT_ + l] * D_);
            aL.x += v.x; aL.y += v.y; aL.z += v.z; aL.w += v.w;
        }
    }

    // ---- text reduce ----
    if (BF16TAB) {
        const int h = lane >> 5, cg = lane & 31, s = wave * 2 + h;
        *reinterpret_cast<float4*>(&red[s][cg * 8])     = make_float4(ta[0], ta[1], ta[2], ta[3]);
        *reinterpret_cast<float4*>(&red[s][cg * 8 + 4]) = make_float4(ta[4], ta[5], ta[6], ta[7]);
    } else {
        *reinterpret_cast<float4*>(&red[wave][lane * 4]) = aT4;
    }
    __syncthreads();
    float t;
    if (BF16TAB)
        t = ((red[0][tid] + red[1][tid]) + (red[2][tid] + red[3][tid]))
          + ((red[4][tid] + red[5][tid]) + (red[6][tid] + red[7][tid]));
    else
        t = (red[0][tid] + red[1][tid]) + (red[2][tid] + red[3][tid]);
    t /= (float)lt;
    const size_t o = (size_t)n * D_ + tid;
    xb_t[o] = f2bf_rne(t);
    __syncthreads();

    // ---- label reduce (reuse red rows 0..3) ----
    *reinterpret_cast<float4*>(&red[wave][lane * 4]) = aL;
    __syncthreads();
    const float lv = (red[0][tid] + red[1][tid]) + (red[2][tid] + red[3][tid]);
    xb_l[o] = f2bf_rne(lv);
}

// ---------------- Kernel B: MFMA projection (x single-bf16, W hi/lo) ----------
// 1024 blocks x 256 thr: block = (node-tile(256), col-quarter(4)); wave owns
// col-tile nt = cq*4 + w. 4 MFMAs/ks: xt*(Wth+Wtl), xl*(Wlh+Wll). 2-stage pipeline.
__global__ __launch_bounds__(256, 4) void proj_kernel(
    const unsigned short* __restrict__ xb_t,
    const unsigned short* __restrict__ xb_l,
    const unsigned short* __restrict__ Wpk,
    const float* __restrict__ w_adap,
    float*       __restrict__ h_comb)     // [NN, D]
{
    __shared__ __align__(16) short ldsX[2][16 * D_];   // 16 KB

    const int tid   = threadIdx.x;
    const int wave  = tid >> 6;
    const int lane  = tid & 63;
    const int ntile = blockIdx.x >> 2;
    const int cq    = blockIdx.x & 3;
    const int base  = ntile * 16;

    // ---- stage x tiles (coalesced int4, XOR-swizzled slots) ----
    #pragma unroll
    for (int r = 0; r < 2; ++r) {
        const int idx = tid + 256 * r;     // 0..511
        const int nd  = idx >> 5, ch = idx & 31;
        const size_t g = (size_t)(base + nd) * D_ + ch * 8;
        const int d = nd * D_ + ((ch ^ (nd & 7)) * 8);
        *reinterpret_cast<int4*>(&ldsX[0][d]) = *reinterpret_cast<const int4*>(&xb_t[g]);
        *reinterpret_cast<int4*>(&ldsX[1][d]) = *reinterpret_cast<const int4*>(&xb_l[g]);
    }
    __syncthreads();

    const int nt  = cq * 4 + wave;      // owned col-tile
    const int row = lane & 15;          // A row (node within tile)
    const int kc  = lane >> 4;          // k-chunk
    const unsigned short* __restrict__ WpB = Wpk + ((size_t)nt * 8) * 4 * 512 + lane * 8;

    f32x4 accT = {0.f, 0.f, 0.f, 0.f};
    f32x4 accL = {0.f, 0.f, 0.f, 0.f};

    bf16x8 cA0, cA1, cB0, cB1, cB2, cB3;
    bf16x8 nA0, nA1, nB0, nB1, nB2, nB3;

    // prologue: load ks=0
    {
        const int aidx = row * D_ + ((kc ^ (row & 7)) * 8);
        cA0 = *reinterpret_cast<const bf16x8*>(&ldsX[0][aidx]);
        cA1 = *reinterpret_cast<const bf16x8*>(&ldsX[1][aidx]);
        const unsigned short* p = WpB;
        cB0 = *reinterpret_cast<const bf16x8*>(p);
        cB1 = *reinterpret_cast<const bf16x8*>(p + 512);
        cB2 = *reinterpret_cast<const bf16x8*>(p + 1024);
        cB3 = *reinterpret_cast<const bf16x8*>(p + 1536);
    }

    #pragma unroll
    for (int ks = 0; ks < 8; ++ks) {
        if (ks < 7) {   // prefetch ks+1 under current MFMAs
            const int aidx = row * D_ + ((((ks + 1) * 4 + kc) ^ (row & 7)) * 8);
            nA0 = *reinterpret_cast<const bf16x8*>(&ldsX[0][aidx]);
            nA1 = *reinterpret_cast<const bf16x8*>(&ldsX[1][aidx]);
            const unsigned short* p = WpB + (size_t)(ks + 1) * 2048;
            nB0 = *reinterpret_cast<const bf16x8*>(p);
            nB1 = *reinterpret_cast<const bf16x8*>(p + 512);
            nB2 = *reinterpret_cast<const bf16x8*>(p + 1024);
            nB3 = *reinterpret_cast<const bf16x8*>(p + 1536);
        }

        accT = __builtin_amdgcn_mfma_f32_16x16x32_bf16(cA0, cB0, accT, 0, 0, 0);
        accT = __builtin_amdgcn_mfma_f32_16x16x32_bf16(cA0, cB1, accT, 0, 0, 0);
        accL = __builtin_amdgcn_mfma_f32_16x16x32_bf16(cA1, cB2, accL, 0, 0, 0);
        accL = __builtin_amdgcn_mfma_f32_16x16x32_bf16(cA1, cB3, accL, 0, 0, 0);

        cA0 = nA0; cA1 = nA1;
        cB0 = nB0; cB1 = nB1; cB2 = nB2; cB3 = nB3;
    }

    // C/D layout (m89-verified): col = lane&15, row = (lane>>4)*4 + reg
    const float w0r = w_adap[0] * (1.0f / (float)NPG_);
    const float w1r = w_adap[1] * (1.0f / (float)NPG_);
    #pragma unroll
    for (int r = 0; r < 4; ++r) {
        const int node = base + kc * 4 + r;
        const int col  = nt * 16 + row;
        const float ht = accT[r] > 0.f ? accT[r] : 0.f;
        const float hl = accL[r] > 0.f ? accL[r] : 0.f;
        h_comb[(size_t)node * D_ + col] = w0r * ht + w1r * hl;
    }
}

// ---------------- Kernel C: per-graph readout + MLP, 4 blocks per graph split Wout ----------------
__global__ __launch_bounds__(256) void graph_kernel(
    const float* __restrict__ h_comb,   // [NN, D]
    const float* __restrict__ W1,       // [D, D]
    const float* __restrict__ b1,       // [D]
    const float* __restrict__ Wout,     // [D, OUT]
    const float* __restrict__ bout,     // [OUT]
    float*       __restrict__ out)      // [BG, OUT]
{
    __shared__ float fused[D_];
    __shared__ float hrow[D_];

    const int bx   = blockIdx.x;
    const int b    = bx >> 2;
    const int part = bx & 3;
    const int tid  = threadIdx.x;

    float acc = 0.f;
    const float* __restrict__ basep = h_comb + (size_t)b * NPG_ * D_ + tid;
    #pragma unroll 8
    for (int n = 0; n < NPG_; ++n) acc += basep[(size_t)n * D_];
    fused[tid] = acc;
    __syncthreads();

    {
        float s0 = 0.f, s1 = 0.f, s2 = 0.f, s3 = 0.f;
        const float* __restrict__ wp = W1 + tid;
        for (int d = 0; d < D_; d += 4) {
            s0 = fmaf(fused[d + 0], wp[(size_t)(d + 0) * D_], s0);
            s1 = fmaf(fused[d + 1], wp[(size_t)(d + 1) * D_], s1);
            s2 = fmaf(fused[d + 2], wp[(size_t)(d + 2) * D_], s2);
            s3 = fmaf(fused[d + 3], wp[(size_t)(d + 3) * D_], s3);
        }
        const float a1 = b1[tid] + ((s0 + s1) + (s2 + s3));
        hrow[tid] = a1 > 0.f ? a1 : 0.f;
    }
    __syncthreads();

    const int j = part * 256 + tid;
    {
        float s0 = 0.f, s1 = 0.f, s2 = 0.f, s3 = 0.f;
        const float* __restrict__ wp = Wout + j;
        for (int d = 0; d < D_; d += 4) {
            s0 = fmaf(hrow[d + 0], wp[(size_t)(d + 0) * OUT_], s0);
            s1 = fmaf(hrow[d + 1], wp[(size_t)(d + 1) * OUT_], s1);
            s2 = fmaf(hrow[d + 2], wp[(size_t)(d + 2) * OUT_], s2);
            s3 = fmaf(hrow[d + 3], wp[(size_t)(d + 3) * OUT_], s3);
        }
        out[(size_t)b * OUT_ + j] = bout[j] + ((s0 + s1) + (s2 + s3));
    }
}

extern "C" void kernel_launch(void* const* d_in, const int* in_sizes, int n_in,
                              void* d_out, int out_size, void* d_ws, size_t ws_size,
                              hipStream_t stream) {
    const int*   text_ids  = (const int*)  d_in[0];
    const int*   label_ids = (const int*)  d_in[1];
    const int*   text_len  = (const int*)  d_in[2];
    const int*   label_len = (const int*)  d_in[3];
    const float* word_emb  = (const float*)d_in[4];
    const float* label_emb = (const float*)d_in[5];
    const float* Wg_text   = (const float*)d_in[6];
    const float* Wg_label  = (const float*)d_in[7];
    const float* w_adap    = (const float*)d_in[8];
    const float* W1        = (const float*)d_in[9];
    const float* b1        = (const float*)d_in[10];
    const float* Wout      = (const float*)d_in[11];
    const float* bout      = (const float*)d_in[12];

    // ws layout (byte offsets):
    //   [0, 4 MB)        h_comb  f32 [NN][D]
    //   [4 MB, 6 MB)     xb_t bf16 [NN][D]
    //   [6 MB, 8 MB)     xb_l bf16 [NN][D]
    //   [8 MB, +512 KB)  Wpk packed bf16 B-fragments
    //   [9 MB, +25.6 MB) wtab bf16 word table (only if ws_size allows)
    char* ws = (char*)d_ws;
    float*          h_comb = (float*)ws;
    unsigned short* xb_t   = (unsigned short*)(ws + (4 << 20));
    unsigned short* xb_l   = (unsigned short*)(ws + (6 << 20));
    unsigned short* Wpk    = (unsigned short*)(ws + (8 << 20));
    unsigned short* wtab   = (unsigned short*)(ws + (9 << 20));
    float*          out    = (float*)d_out;

    const size_t need = (size_t)(9 << 20) + (size_t)VOCAB_ * D_ * 2;
    const bool useBf16 = ws_size >= need;
    const int convBlocks = useBf16 ? 2048 : 0;

    prep_kernel<<<convBlocks + 256, 256, 0, stream>>>(
        word_emb, Wg_text, Wg_label, convBlocks, wtab, Wpk);

    if (useBf16) {
        gather_kernel<true><<<NN, 256, 0, stream>>>(
            text_ids, label_ids, text_len, label_len,
            word_emb, wtab, label_emb, xb_t, xb_l);
    } else {
        gather_kernel<false><<<NN, 256, 0, stream>>>(
            text_ids, label_ids, text_len, label_len,
            word_emb, wtab, label_emb, xb_t, xb_l);
    }

    proj_kernel<<<NN / 16 * 4, 256, 0, stream>>>(
        xb_t, xb_l, Wpk, w_adap, h_comb);

    graph_kernel<<<BG * 4, 256, 0, stream>>>(
        h_comb, W1, b1, Wout, bout, out);
}

// Round 13
// 74.219 us; speedup vs baseline: 1.9948x; 1.0160x over previous
//
#include <hip/hip_runtime.h>

#define NN      4096   // total nodes
#define BG      64     // graphs
#define NPG_    64     // nodes per graph
#define LT_     128
#define LL_     32
#define D_      256
#define OUT_    1024
#define VOCAB_  50000

typedef __attribute__((ext_vector_type(8))) short bf16x8;   // 8 bf16 = 4 VGPR
typedef __attribute__((ext_vector_type(4))) float f32x4;

__device__ __forceinline__ unsigned short f2bf_rne(float f) {
    union { float f; unsigned u; } a; a.f = f;
    const unsigned r = a.u + 0x7FFFu + ((a.u >> 16) & 1u);
    return (unsigned short)(r >> 16);
}
__device__ __forceinline__ float bf2f(unsigned short h) {
    union { unsigned u; float f; } a; a.u = ((unsigned)h) << 16;
    return a.f;
}
// split f32 into bf16 hi + lo; v ~= hi + lo, err <= 2^-18 |v| (W pack only)
__device__ __forceinline__ void split_bf16(float v, unsigned short& hi, unsigned short& lo) {
    union { float f; unsigned u; } a; a.f = v;
    const unsigned hu = (a.u + 0x8000u) & 0xFFFF0000u;
    union { unsigned u; float f; } h; h.u = hu;
    const float r = v - h.f;                  // exact
    union { float f; unsigned u; } b; b.f = r;
    hi = (unsigned short)(hu >> 16);
    lo = (unsigned short)(((b.u + 0x8000u) & 0xFFFF0000u) >> 16);
}

// ---------------- K1: word_emb->bf16 conv  +  W pack  +  LABEL gather ----------------
// Blocks [0, convBlocks): grid-stride RNE conversion of word_emb.
// Blocks [convBlocks, +256): pack W into Wpk[nt][ks][plane(4)][lane][e].
// Blocks [convBlocks+256, +NN): per-node label gather (f32 table) -> xb_l bf16.
// The three roles are independent; conv first so its stream starts immediately.
__global__ __launch_bounds__(256) void prep_label_kernel(
    const float* __restrict__ word_emb,
    const float* __restrict__ Wg_text,
    const float* __restrict__ Wg_label,
    const int convBlocks,
    const int*   __restrict__ label_ids,
    const int*   __restrict__ label_len,
    const float* __restrict__ label_emb,
    unsigned short* __restrict__ wtab,
    unsigned short* __restrict__ Wpk,
    unsigned short* __restrict__ xb_l)   // [NN, D] bf16
{
    const int tid = threadIdx.x;

    if (blockIdx.x < convBlocks) {
        const int total4 = VOCAB_ * D_ / 4;
        const int stride = convBlocks * 256;
        for (int i = blockIdx.x * 256 + tid; i < total4; i += stride) {
            const float4 v = *reinterpret_cast<const float4*>(word_emb + (size_t)i * 4);
            ushort4 o;
            o.x = f2bf_rne(v.x); o.y = f2bf_rne(v.y);
            o.z = f2bf_rne(v.z); o.w = f2bf_rne(v.w);
            *reinterpret_cast<ushort4*>(wtab + (size_t)i * 4) = o;
        }
        return;
    }
    if (blockIdx.x < convBlocks + 256) {
        const int b   = blockIdx.x - convBlocks;   // mat(2) x nt(16) x ks(8)
        const int mat = b >> 7;
        const int nt  = (b >> 3) & 15;
        const int ks  = b & 7;
        const float* __restrict__ W = mat ? Wg_label : Wg_text;
        #pragma unroll
        for (int r = 0; r < 2; ++r) {
            const int idx = tid + 256 * r;     // 0..511 = 32 k x 16 cols
            const int kl  = idx >> 4;
            const int c16 = idx & 15;
            const int k   = ks * 32 + kl;
            const float v = W[(size_t)k * D_ + nt * 16 + c16];
            unsigned short h, l;
            split_bf16(v, h, l);
            const int lane = c16 + 16 * ((kl >> 3) & 3);
            const int e    = kl & 7;
            const size_t pb = (((size_t)nt * 8 + ks) * 4 + mat * 2) * 512 + lane * 8 + e;
            Wpk[pb]       = h;
            Wpk[pb + 512] = l;
        }
        return;
    }

    // ---- label gather role (proven 4-way wave-split f32 path) ----
    __shared__ int   sIds[LL_];
    __shared__ float red[4][D_];

    const int n    = blockIdx.x - convBlocks - 256;
    const int wave = tid >> 6;
    const int lane = tid & 63;

    if (tid < LL_) sIds[tid] = label_ids[(size_t)n * LL_ + tid];
    const int ll = label_len[n];
    __syncthreads();

    float4 aL = make_float4(0.f, 0.f, 0.f, 0.f);
    {
        const float* __restrict__ bp = label_emb + (size_t)lane * 4;
        #pragma unroll 8
        for (int l = wave; l < ll; l += 4) {
            const float4 v = *reinterpret_cast<const float4*>(bp + (size_t)sIds[l] * D_);
            aL.x += v.x; aL.y += v.y; aL.z += v.z; aL.w += v.w;
        }
    }
    *reinterpret_cast<float4*>(&red[wave][lane * 4]) = aL;
    __syncthreads();
    const float lv = (red[0][tid] + red[1][tid]) + (red[2][tid] + red[3][tid]);
    xb_l[(size_t)n * D_ + tid] = f2bf_rne(lv);
}

// ---------------- K2: TEXT gather -> xb_t bf16 ----------------
// BF16TAB: rows from bf16 table, 16B/lane = 8 cols, lane-halves take different
// rows -> 8 sub-streams. Fallback: f32 table, 4-way split.
template<bool BF16TAB>
__global__ __launch_bounds__(256) void textg_kernel(
    const int*   __restrict__ text_ids,
    const int*   __restrict__ text_len,
    const float* __restrict__ word_emb,
    const unsigned short* __restrict__ wtab,
    unsigned short* __restrict__ xb_t)   // [NN, D] bf16
{
    __shared__ int   sIds[LT_];
    __shared__ float red[8][D_];

    const int n    = blockIdx.x;
    const int tid  = threadIdx.x;
    const int wave = tid >> 6;
    const int lane = tid & 63;

    if (tid < LT_) sIds[tid] = text_ids[(size_t)n * LT_ + tid];
    const int lt = text_len[n];
    __syncthreads();

    float t;
    if (BF16TAB) {
        float ta[8];
        #pragma unroll
        for (int j = 0; j < 8; ++j) ta[j] = 0.f;
        const int h  = lane >> 5;
        const int cg = lane & 31;
        const int s  = wave * 2 + h;               // sub-stream 0..7
        const unsigned short* __restrict__ bp = wtab + cg * 8;
        #pragma unroll 4
        for (int l = s; l < lt; l += 8) {
            const bf16x8 v = *reinterpret_cast<const bf16x8*>(bp + (size_t)sIds[l] * D_);
            #pragma unroll
            for (int j = 0; j < 8; ++j) ta[j] += bf2f((unsigned short)v[j]);
        }
        *reinterpret_cast<float4*>(&red[s][cg * 8])     = make_float4(ta[0], ta[1], ta[2], ta[3]);
        *reinterpret_cast<float4*>(&red[s][cg * 8 + 4]) = make_float4(ta[4], ta[5], ta[6], ta[7]);
        __syncthreads();
        t = ((red[0][tid] + red[1][tid]) + (red[2][tid] + red[3][tid]))
          + ((red[4][tid] + red[5][tid]) + (red[6][tid] + red[7][tid]));
    } else {
        float4 a4 = make_float4(0.f, 0.f, 0.f, 0.f);
        const float* __restrict__ bp = word_emb + (size_t)lane * 4;
        #pragma unroll 8
        for (int l = wave; l < lt; l += 4) {
            const float4 v = *reinterpret_cast<const float4*>(bp + (size_t)sIds[l] * D_);
            a4.x += v.x; a4.y += v.y; a4.z += v.z; a4.w += v.w;
        }
        *reinterpret_cast<float4*>(&red[wave][lane * 4]) = a4;
        __syncthreads();
        t = (red[0][tid] + red[1][tid]) + (red[2][tid] + red[3][tid]);
    }
    t /= (float)lt;
    xb_t[(size_t)n * D_ + tid] = f2bf_rne(t);
}

// ---------------- K3: MFMA projection (x single-bf16, W hi/lo) ----------
// 1024 blocks x 256 thr: block = (node-tile(256), col-quarter(4)); wave owns
// col-tile nt = cq*4 + w. 4 MFMAs/ks. 2-stage pipeline. (proven R12)
__global__ __launch_bounds__(256, 4) void proj_kernel(
    const unsigned short* __restrict__ xb_t,
    const unsigned short* __restrict__ xb_l,
    const unsigned short* __restrict__ Wpk,
    const float* __restrict__ w_adap,
    float*       __restrict__ h_comb)     // [NN, D]
{
    __shared__ __align__(16) short ldsX[2][16 * D_];   // 16 KB

    const int tid   = threadIdx.x;
    const int wave  = tid >> 6;
    const int lane  = tid & 63;
    const int ntile = blockIdx.x >> 2;
    const int cq    = blockIdx.x & 3;
    const int base  = ntile * 16;

    #pragma unroll
    for (int r = 0; r < 2; ++r) {
        const int idx = tid + 256 * r;     // 0..511
        const int nd  = idx >> 5, ch = idx & 31;
        const size_t g = (size_t)(base + nd) * D_ + ch * 8;
        const int d = nd * D_ + ((ch ^ (nd & 7)) * 8);
        *reinterpret_cast<int4*>(&ldsX[0][d]) = *reinterpret_cast<const int4*>(&xb_t[g]);
        *reinterpret_cast<int4*>(&ldsX[1][d]) = *reinterpret_cast<const int4*>(&xb_l[g]);
    }
    __syncthreads();

    const int nt  = cq * 4 + wave;
    const int row = lane & 15;
    const int kc  = lane >> 4;
    const unsigned short* __restrict__ WpB = Wpk + ((size_t)nt * 8) * 4 * 512 + lane * 8;

    f32x4 accT = {0.f, 0.f, 0.f, 0.f};
    f32x4 accL = {0.f, 0.f, 0.f, 0.f};

    bf16x8 cA0, cA1, cB0, cB1, cB2, cB3;
    bf16x8 nA0, nA1, nB0, nB1, nB2, nB3;

    {
        const int aidx = row * D_ + ((kc ^ (row & 7)) * 8);
        cA0 = *reinterpret_cast<const bf16x8*>(&ldsX[0][aidx]);
        cA1 = *reinterpret_cast<const bf16x8*>(&ldsX[1][aidx]);
        const unsigned short* p = WpB;
        cB0 = *reinterpret_cast<const bf16x8*>(p);
        cB1 = *reinterpret_cast<const bf16x8*>(p + 512);
        cB2 = *reinterpret_cast<const bf16x8*>(p + 1024);
        cB3 = *reinterpret_cast<const bf16x8*>(p + 1536);
    }

    #pragma unroll
    for (int ks = 0; ks < 8; ++ks) {
        if (ks < 7) {
            const int aidx = row * D_ + ((((ks + 1) * 4 + kc) ^ (row & 7)) * 8);
            nA0 = *reinterpret_cast<const bf16x8*>(&ldsX[0][aidx]);
            nA1 = *reinterpret_cast<const bf16x8*>(&ldsX[1][aidx]);
            const unsigned short* p = WpB + (size_t)(ks + 1) * 2048;
            nB0 = *reinterpret_cast<const bf16x8*>(p);
            nB1 = *reinterpret_cast<const bf16x8*>(p + 512);
            nB2 = *reinterpret_cast<const bf16x8*>(p + 1024);
            nB3 = *reinterpret_cast<const bf16x8*>(p + 1536);
        }

        accT = __builtin_amdgcn_mfma_f32_16x16x32_bf16(cA0, cB0, accT, 0, 0, 0);
        accT = __builtin_amdgcn_mfma_f32_16x16x32_bf16(cA0, cB1, accT, 0, 0, 0);
        accL = __builtin_amdgcn_mfma_f32_16x16x32_bf16(cA1, cB2, accL, 0, 0, 0);
        accL = __builtin_amdgcn_mfma_f32_16x16x32_bf16(cA1, cB3, accL, 0, 0, 0);

        cA0 = nA0; cA1 = nA1;
        cB0 = nB0; cB1 = nB1; cB2 = nB2; cB3 = nB3;
    }

    const float w0r = w_adap[0] * (1.0f / (float)NPG_);
    const float w1r = w_adap[1] * (1.0f / (float)NPG_);
    #pragma unroll
    for (int r = 0; r < 4; ++r) {
        const int node = base + kc * 4 + r;
        const int col  = nt * 16 + row;
        const float ht = accT[r] > 0.f ? accT[r] : 0.f;
        const float hl = accL[r] > 0.f ? accL[r] : 0.f;
        h_comb[(size_t)node * D_ + col] = w0r * ht + w1r * hl;
    }
}

// ---------------- K4: per-graph readout + MLP ----------------
__global__ __launch_bounds__(256) void graph_kernel(
    const float* __restrict__ h_comb,
    const float* __restrict__ W1,
    const float* __restrict__ b1,
    const float* __restrict__ Wout,
    const float* __restrict__ bout,
    float*       __restrict__ out)
{
    __shared__ float fused[D_];
    __shared__ float hrow[D_];

    const int bx   = blockIdx.x;
    const int b    = bx >> 2;
    const int part = bx & 3;
    const int tid  = threadIdx.x;

    float acc = 0.f;
    const float* __restrict__ basep = h_comb + (size_t)b * NPG_ * D_ + tid;
    #pragma unroll 8
    for (int n = 0; n < NPG_; ++n) acc += basep[(size_t)n * D_];
    fused[tid] = acc;
    __syncthreads();

    {
        float s0 = 0.f, s1 = 0.f, s2 = 0.f, s3 = 0.f;
        const float* __restrict__ wp = W1 + tid;
        for (int d = 0; d < D_; d += 4) {
            s0 = fmaf(fused[d + 0], wp[(size_t)(d + 0) * D_], s0);
            s1 = fmaf(fused[d + 1], wp[(size_t)(d + 1) * D_], s1);
            s2 = fmaf(fused[d + 2], wp[(size_t)(d + 2) * D_], s2);
            s3 = fmaf(fused[d + 3], wp[(size_t)(d + 3) * D_], s3);
        }
        const float a1 = b1[tid] + ((s0 + s1) + (s2 + s3));
        hrow[tid] = a1 > 0.f ? a1 : 0.f;
    }
    __syncthreads();

    const int j = part * 256 + tid;
    {
        float s0 = 0.f, s1 = 0.f, s2 = 0.f, s3 = 0.f;
        const float* __restrict__ wp = Wout + j;
        for (int d = 0; d < D_; d += 4) {
            s0 = fmaf(hrow[d + 0], wp[(size_t)(d + 0) * OUT_], s0);
            s1 = fmaf(hrow[d + 1], wp[(size_t)(d + 1) * OUT_], s1);
            s2 = fmaf(hrow[d + 2], wp[(size_t)(d + 2) * OUT_], s2);
            s3 = fmaf(hrow[d + 3], wp[(size_t)(d + 3) * OUT_], s3);
        }
        out[(size_t)b * OUT_ + j] = bout[j] + ((s0 + s1) + (s2 + s3));
    }
}

extern "C" void kernel_launch(void* const* d_in, const int* in_sizes, int n_in,
                              void* d_out, int out_size, void* d_ws, size_t ws_size,
                              hipStream_t stream) {
    const int*   text_ids  = (const int*)  d_in[0];
    const int*   label_ids = (const int*)  d_in[1];
    const int*   text_len  = (const int*)  d_in[2];
    const int*   label_len = (const int*)  d_in[3];
    const float* word_emb  = (const float*)d_in[4];
    const float* label_emb = (const float*)d_in[5];
    const float* Wg_text   = (const float*)d_in[6];
    const float* Wg_label  = (const float*)d_in[7];
    const float* w_adap    = (const float*)d_in[8];
    const float* W1        = (const float*)d_in[9];
    const float* b1        = (const float*)d_in[10];
    const float* Wout      = (const float*)d_in[11];
    const float* bout      = (const float*)d_in[12];

    // ws layout (byte offsets):
    //   [0, 4 MB)        h_comb  f32 [NN][D]
    //   [4 MB, 6 MB)     xb_t bf16 [NN][D]
    //   [6 MB, 8 MB)     xb_l bf16 [NN][D]
    //   [8 MB, +512 KB)  Wpk packed bf16 B-fragments
    //   [9 MB, +25.6 MB) wtab bf16 word table (only if ws_size allows)
    char* ws = (char*)d_ws;
    float*          h_comb = (float*)ws;
    unsigned short* xb_t   = (unsigned short*)(ws + (4 << 20));
    unsigned short* xb_l   = (unsigned short*)(ws + (6 << 20));
    unsigned short* Wpk    = (unsigned short*)(ws + (8 << 20));
    unsigned short* wtab   = (unsigned short*)(ws + (9 << 20));
    float*          out    = (float*)d_out;

    const size_t need = (size_t)(9 << 20) + (size_t)VOCAB_ * D_ * 2;
    const bool useBf16 = ws_size >= need;
    const int convBlocks = useBf16 ? 2048 : 0;

    prep_label_kernel<<<convBlocks + 256 + NN, 256, 0, stream>>>(
        word_emb, Wg_text, Wg_label, convBlocks,
        label_ids, label_len, label_emb,
        wtab, Wpk, xb_l);

    if (useBf16) {
        textg_kernel<true><<<NN, 256, 0, stream>>>(
            text_ids, text_len, word_emb, wtab, xb_t);
    } else {
        textg_kernel<false><<<NN, 256, 0, stream>>>(
            text_ids, text_len, word_emb, wtab, xb_t);
    }

    proj_kernel<<<NN / 16 * 4, 256, 0, stream>>>(
        xb_t, xb_l, Wpk, w_adap, h_comb);

    graph_kernel<<<BG * 4, 256, 0, stream>>>(
        h_comb, W1, b1, Wout, bout, out);
}